// Round 7
// baseline (241.823 us; speedup 1.0000x reference)
//
#include <hip/hip_runtime.h>
#include <hip/hip_bf16.h>

#define N_NODES_C 25000
#define N_HEDGES_C 12500
#define NNZ_C 400000
#define C_IN_C 128
#define HID_C 256
#define LN_EPS_C 1e-5f
#define CSR_STRIDE 64

typedef unsigned short ushort_t;
typedef __attribute__((ext_vector_type(8))) short short8;
typedef __attribute__((ext_vector_type(4))) float f32x4;

union U4S8 { uint4 u; short8 s; };

__device__ __forceinline__ float ldsel(const void* p, size_t i, bool f32) {
    return f32 ? ((const float*)p)[i] : __bfloat162float(((const __hip_bfloat16*)p)[i]);
}
__device__ __forceinline__ int ldidx(const void* p, size_t i, bool i64) {
    return i64 ? (int)((const long long*)p)[i] : ((const int*)p)[i];
}
__device__ __forceinline__ ushort_t bfbits(float f) {
    union { float f; unsigned u; } v; v.f = f;
    unsigned r = v.u + 0x7FFF + ((v.u >> 16) & 1);
    return (ushort_t)(r >> 16);
}
__device__ __forceinline__ float blo(unsigned u) {
    union { unsigned u; float f; } v; v.u = u << 16; return v.f;
}
__device__ __forceinline__ float bhi(unsigned u) {
    union { unsigned u; float f; } v; v.u = u & 0xFFFF0000u; return v.f;
}

// ---------------------------------------------------------------------------
// init (r6): block 0 = dtype sniff; rest zero counters + vb dummy row + ea
// dummy slots.  attn clamps pad slots, so no scsr dummy-fill needed.
// ---------------------------------------------------------------------------
#define INIT_GRID 148   // 1 + (37500+128+4 -> 37632)/256
__global__ void __launch_bounds__(256)
init_kernel(const unsigned* __restrict__ x0w, const unsigned* __restrict__ idxw,
            int* __restrict__ flags, unsigned* __restrict__ cnts,
            unsigned* __restrict__ vb32, unsigned* __restrict__ ea32) {
    int bid = blockIdx.x;
    if (bid == 0) {
        __shared__ int cnt[2];
        int t = threadIdx.x;
        if (t < 2) cnt[t] = 0;
        __syncthreads();
        int c0 = 0, c1 = 0;
        for (int k = 0; k < 4; k++) {
            unsigned w = x0w[t * 4 + k];
            unsigned elo = (w >> 7) & 0xFF;
            if (elo >= 100 && elo <= 134) c0++;
            if (idxw[2 * (t * 4 + k) + 1] == 0) c1++;
        }
        atomicAdd(&cnt[0], c0);
        atomicAdd(&cnt[1], c1);
        __syncthreads();
        if (t == 0) {
            flags[0] = (cnt[0] < 512) ? 1 : 0;  // 1 => floats are f32
            flags[1] = (cnt[1] >= 512) ? 1 : 0; // 1 => indices are int64
        }
        return;
    }
    int i = (bid - 1) * 256 + threadIdx.x;
    if (i < 37500) { cnts[i] = 0u; return; }
    i -= 37500;
    if (i < 128) { vb32[25000 * 128 + i] = 0u; return; }
    i -= 128;
    if (i < 4) ea32[100000 + i] = 0u;
}

// ---------------------------------------------------------------------------
// mega kernel (r7): fill ∥ gemm_x0 ∥ prep in ONE dispatch.
//  blocks [0, 3128): XCD-sliced padded-CSR fill (proven r4/r6).
//  blocks [3128, 3910): gemm_x0 + fused expalpha dir-1, SELF-CONTAINED —
//    transposes V1->Bs on the fly (bit-identical bfbits rounding to the old
//    Vt1b) and computes the kq1 table in-block (same serial-d FMA order as
//    prep did) -> depends only on init, so it hides under fill's ~43us.
//  blocks [3910, 5204): prep minus kq1/Vt1b (now dead): kq2, Vt2b, W
//    transposes, f32 tables.
// No cross-block deps inside the dispatch (gemm reads inputs+flags only).
// ---------------------------------------------------------------------------
#define FILL_CHUNK 1024
#define FILL_NCHUNK ((NNZ_C + FILL_CHUNK - 1) / FILL_CHUNK)   // 391
#define FILL_BLOCKS (8 * FILL_NCHUNK)                         // 3128
#define HSLICE_SZ 1563
#define NSLICE_SZ 3125
#define GEMM_BLOCKS (2 * ((N_NODES_C + 63) / 64))             // 782
#define PREP_TOTAL 331264
#define PREP_BLOCKS (PREP_TOTAL / 256)                        // 1294
#define MEGA_GRID (FILL_BLOCKS + GEMM_BLOCKS + PREP_BLOCKS)   // 5204

__global__ void __launch_bounds__(256)
mega_kernel(const void* __restrict__ node_idx, const void* __restrict__ hedge_idx,
            int* __restrict__ fill_h, int* __restrict__ fill_n,
            ushort_t* __restrict__ scsr_h, ushort_t* __restrict__ scsr_n,
            const void* __restrict__ x0, ushort_t* __restrict__ vbC,
            float* __restrict__ ea,
            const void* __restrict__ K1, const void* __restrict__ Q1,
            const void* __restrict__ V1,
            const void* __restrict__ K2, const void* __restrict__ Q2,
            const void* __restrict__ V2,
            const void* __restrict__ W1a, const void* __restrict__ W2a,
            const void* __restrict__ W1b, const void* __restrict__ W2b,
            const void* __restrict__ G0a, const void* __restrict__ B0a,
            const void* __restrict__ G1a, const void* __restrict__ B1a,
            const void* __restrict__ G0b, const void* __restrict__ B0b,
            const void* __restrict__ G1b, const void* __restrict__ B1b,
            const int* __restrict__ flags,
            float* __restrict__ kq2,
            ushort_t* __restrict__ Vt2b,
            ushort_t* __restrict__ W1tA, ushort_t* __restrict__ W2tA,
            ushort_t* __restrict__ W1tB, ushort_t* __restrict__ W2tB,
            float* __restrict__ qgb1, float* __restrict__ ep1,
            float* __restrict__ qgb2, float* __restrict__ ep2) {
    __shared__ ushort_t As[64 * 72];
    __shared__ ushort_t Bs[128 * 72];
    __shared__ float kqs[512];
    // ---------------- section 1: fill ----------------
    if (blockIdx.x < FILL_BLOCKS) {
        bool i64 = flags[1] != 0;
        int s = blockIdx.x & 7;
        int chunk = blockIdx.x >> 3;
        int e0 = chunk * FILL_CHUNK;
        int e1 = e0 + FILL_CHUNK; if (e1 > NNZ_C) e1 = NNZ_C;
        int hlo = s * HSLICE_SZ, hhi = hlo + HSLICE_SZ;
        int nlo = s * NSLICE_SZ, nhi = nlo + NSLICE_SZ;
        for (int e = e0 + threadIdx.x; e < e1; e += 256) {
            int nd = ldidx(node_idx, e, i64);
            int he = ldidx(hedge_idx, e, i64);
            if (he >= hlo && he < hhi) {
                int p = atomicAdd(&fill_h[he], 1);
                if (p < CSR_STRIDE) scsr_h[(he << 6) + p] = (ushort_t)nd;
            }
            if (nd >= nlo && nd < nhi) {
                int p = atomicAdd(&fill_n[nd], 1);
                if (p < CSR_STRIDE) scsr_n[(nd << 6) + p] = (ushort_t)he;
            }
        }
        return;
    }
    // ---------------- section 2: gemm_x0 + expalpha dir-1 ----------------
    if (blockIdx.x < FILL_BLOCKS + GEMM_BLOCKS) {
        int gi = blockIdx.x - FILL_BLOCKS;
        int bx = gi >> 1, by = gi & 1;
        int row0 = bx * 64, col0 = by * 128;
        bool doEa = (by == 0);
        bool f32 = flags[0] != 0;
        int tid = threadIdx.x;
        int w = tid >> 6, lane = tid & 63;
        int l15 = lane & 15, kg = lane >> 4;
        int wr = w >> 1, wc = w & 1;
        int h0 = col0 >> 6;
        if (doEa) {
            for (int i = tid; i < 512; i += 256) {
                int h = i >> 7, c = i & 127;
                float s = 0.f;
                for (int d = 0; d < 64; d++)
                    s += ldsel(K1, (size_t)(h * 128 + c) * 64 + d, f32) * ldsel(Q1, h * 64 + d, f32);
                kqs[i] = s;
            }
        }
        __syncthreads();
        f32x4 acc[2][4] = {{{0.f,0.f,0.f,0.f},{0.f,0.f,0.f,0.f},{0.f,0.f,0.f,0.f},{0.f,0.f,0.f,0.f}},
                           {{0.f,0.f,0.f,0.f},{0.f,0.f,0.f,0.f},{0.f,0.f,0.f,0.f},{0.f,0.f,0.f,0.f}}};
        float hd[2][4] = {{0.f,0.f,0.f,0.f},{0.f,0.f,0.f,0.f}};
        int r_ = tid >> 3, ch = tid & 7;
        for (int k0 = 0; k0 < C_IN_C; k0 += 64) {
#pragma unroll
            for (int p = 0; p < 2; p++) {
                int r = p * 32 + r_;
                uint4 av = {0u,0u,0u,0u};
                int gr = row0 + r;
                if (gr < N_NODES_C) {
                    float fv[8];
                    if (!f32) {
                        av = *(const uint4*)((const ushort_t*)x0 + (size_t)gr * C_IN_C + k0 + ch * 8);
                        if (doEa) {
                            unsigned* uw = (unsigned*)&av;
#pragma unroll
                            for (int jj = 0; jj < 4; jj++) { fv[2 * jj] = blo(uw[jj]); fv[2 * jj + 1] = bhi(uw[jj]); }
                        }
                    } else {
                        const float* ap = (const float*)x0 + (size_t)gr * C_IN_C + k0 + ch * 8;
                        float4 f0 = *(const float4*)ap;
                        float4 f1 = *(const float4*)(ap + 4);
                        av.x = (unsigned)bfbits(f0.x) | ((unsigned)bfbits(f0.y) << 16);
                        av.y = (unsigned)bfbits(f0.z) | ((unsigned)bfbits(f0.w) << 16);
                        av.z = (unsigned)bfbits(f1.x) | ((unsigned)bfbits(f1.y) << 16);
                        av.w = (unsigned)bfbits(f1.z) | ((unsigned)bfbits(f1.w) << 16);
                        if (doEa) {
                            fv[0] = f0.x; fv[1] = f0.y; fv[2] = f0.z; fv[3] = f0.w;
                            fv[4] = f1.x; fv[5] = f1.y; fv[6] = f1.z; fv[7] = f1.w;
                        }
                    }
                    if (doEa) {
                        int c = k0 + ch * 8;
#pragma unroll
                        for (int h = 0; h < 4; h++) {
                            float s = 0.f;
#pragma unroll
                            for (int j = 0; j < 8; j++) s += fv[j] * kqs[h * 128 + c + j];
                            hd[p][h] += s;
                        }
                    }
                }
                *(uint4*)&As[r * 72 + ch * 8] = av;
            }
            // B staging: transpose V1[h][c][d] -> Bs[(q*64+d)*72 + (c-k0)]
            if (!f32) {
#pragma unroll
                for (int q = 0; q < 2; q++) {
                    const ushort_t* vsrc = (const ushort_t*)V1 + ((size_t)(h0 + q) * 128 + k0) * 64;
#pragma unroll
                    for (int p = 0; p < 2; p++) {
                        int eidx = (p * 256 + tid) * 8;
                        int cr = eidx >> 6, d = eidx & 63;
                        uint4 v = *(const uint4*)(vsrc + eidx);
                        const ushort_t* vs = (const ushort_t*)&v;
#pragma unroll
                        for (int jj = 0; jj < 8; jj++)
                            Bs[(q * 64 + d + jj) * 72 + cr] = vs[jj];
                    }
                }
            } else {
#pragma unroll
                for (int q = 0; q < 2; q++) {
                    const float* vsrc = (const float*)V1 + ((size_t)(h0 + q) * 128 + k0) * 64;
#pragma unroll
                    for (int p = 0; p < 4; p++) {
                        int eidx = (p * 256 + tid) * 4;
                        int cr = eidx >> 6, d = eidx & 63;
                        float4 f = *(const float4*)(vsrc + eidx);
                        Bs[(q * 64 + d + 0) * 72 + cr] = bfbits(f.x);
                        Bs[(q * 64 + d + 1) * 72 + cr] = bfbits(f.y);
                        Bs[(q * 64 + d + 2) * 72 + cr] = bfbits(f.z);
                        Bs[(q * 64 + d + 3) * 72 + cr] = bfbits(f.w);
                    }
                }
            }
            __syncthreads();
#pragma unroll
            for (int kk = 0; kk < 2; kk++) {
                U4S8 a0_, a1_;
                a0_.u = *(const uint4*)&As[(32 * wr + l15) * 72 + kk * 32 + kg * 8];
                a1_.u = *(const uint4*)&As[(32 * wr + 16 + l15) * 72 + kk * 32 + kg * 8];
#pragma unroll
                for (int n = 0; n < 4; n++) {
                    U4S8 b; b.u = *(const uint4*)&Bs[(64 * wc + 16 * n + l15) * 72 + kk * 32 + kg * 8];
                    acc[0][n] = __builtin_amdgcn_mfma_f32_16x16x32_bf16(a0_.s, b.s, acc[0][n], 0, 0, 0);
                    acc[1][n] = __builtin_amdgcn_mfma_f32_16x16x32_bf16(a1_.s, b.s, acc[1][n], 0, 0, 0);
                }
            }
            __syncthreads();
        }
#pragma unroll
        for (int m = 0; m < 2; m++) {
#pragma unroll
            for (int n = 0; n < 4; n++) {
#pragma unroll
                for (int rr = 0; rr < 4; rr++) {
                    int row = row0 + 32 * wr + 16 * m + kg * 4 + rr;
                    if (row < N_NODES_C)
                        vbC[(size_t)row * 256 + col0 + 64 * wc + 16 * n + l15] = bfbits(acc[m][n][rr]);
                }
            }
        }
        if (doEa) {
#pragma unroll
            for (int p = 0; p < 2; p++) {
#pragma unroll
                for (int msk = 1; msk < 8; msk <<= 1) {
                    hd[p][0] += __shfl_xor(hd[p][0], msk);
                    hd[p][1] += __shfl_xor(hd[p][1], msk);
                    hd[p][2] += __shfl_xor(hd[p][2], msk);
                    hd[p][3] += __shfl_xor(hd[p][3], msk);
                }
                if (ch == 0) {
                    int row = row0 + p * 32 + r_;
                    if (row < N_NODES_C) {
                        float4 o;
                        o.x = __expf(hd[p][0]); o.y = __expf(hd[p][1]);
                        o.z = __expf(hd[p][2]); o.w = __expf(hd[p][3]);
                        *(float4*)(ea + (size_t)row * 4) = o;
                    }
                }
            }
        }
        return;
    }
    // ---------------- section 3: prep (minus kq1/Vt1b) ----------------
    bool f32 = flags[0] != 0;
    size_t i = (size_t)(blockIdx.x - FILL_BLOCKS - GEMM_BLOCKS) * 256 + threadIdx.x;
    if (i >= PREP_TOTAL) return;
    if (i < 1024) {
        int h = (int)(i >> 8), c = (int)(i & 255);
        float s = 0.f;
        for (int d = 0; d < 64; d++)
            s += ldsel(K2, (size_t)(h * 256 + c) * 64 + d, f32) * ldsel(Q2, h * 64 + d, f32);
        kq2[h * 256 + c] = s;
        return;
    }
    i -= 1024;
    if (i < 65536) {
        int j = (int)(i >> 8), c = (int)(i & 255);
        int h = j >> 6, d = j & 63;
        Vt2b[i] = bfbits(ldsel(V2, (size_t)(h * 256 + c) * 64 + d, f32));
        return;
    }
    i -= 65536;
    if (i < 65536) { int n = (int)(i >> 8), k = (int)(i & 255);
        W1tA[i] = bfbits(ldsel(W1a, (size_t)k * 256 + n, f32)); return; }
    i -= 65536;
    if (i < 65536) { int n = (int)(i >> 8), k = (int)(i & 255);
        W2tA[i] = bfbits(ldsel(W2a, (size_t)k * 256 + n, f32)); return; }
    i -= 65536;
    if (i < 65536) { int n = (int)(i >> 8), k = (int)(i & 255);
        W1tB[i] = bfbits(ldsel(W1b, (size_t)k * 256 + n, f32)); return; }
    i -= 65536;
    if (i < 65536) { int n = (int)(i >> 8), k = (int)(i & 255);
        W2tB[i] = bfbits(ldsel(W2b, (size_t)k * 256 + n, f32)); return; }
    i -= 65536;
    {
        int which = (int)(i >> 8);
        int j = (int)(i & 255);
        const void* src; float* dst;
        switch (which) {
            case 0: src = Q1;  dst = qgb1;       break;
            case 1: src = G0a; dst = qgb1 + 256; break;
            case 2: src = B0a; dst = qgb1 + 512; break;
            case 3: src = G1a; dst = ep1;        break;
            case 4: src = B1a; dst = ep1 + 256;  break;
            case 5: src = Q2;  dst = qgb2;       break;
            case 6: src = G0b; dst = qgb2 + 256; break;
            case 7: src = B0b; dst = qgb2 + 512; break;
            case 8: src = G1b; dst = ep2;        break;
            default: src = B1b; dst = ep2 + 256;  break;
        }
        dst[j] = ldsel(src, j, f32);
    }
}

// ---------------------------------------------------------------------------
// Fused MLP + LN1 (+ dir-1 extras) — r4 retile: 32 rows/block,
// register-prefetch staging.  8 waves: wave w computes rows 16*(w>>2)..+16,
// cols 64*(w&3)..+64 (acc[4]).  LDS ~59K -> 2 blocks/CU.
// ---------------------------------------------------------------------------
#define LOADB4(SRC, KO) { \
    bv0 = *(const uint4*)((SRC) + (size_t)rb * 256 + (KO) + cb * 8); \
    bv1 = *(const uint4*)((SRC) + (size_t)(rb + 64) * 256 + (KO) + cb * 8); \
    bv2 = *(const uint4*)((SRC) + (size_t)(rb + 128) * 256 + (KO) + cb * 8); \
    bv3 = *(const uint4*)((SRC) + (size_t)(rb + 192) * 256 + (KO) + cb * 8); }
#define WRITEB4() { \
    *(uint4*)&Bs[rb * 72 + cb * 8] = bv0; \
    *(uint4*)&Bs[(rb + 64) * 72 + cb * 8] = bv1; \
    *(uint4*)&Bs[(rb + 128) * 72 + cb * 8] = bv2; \
    *(uint4*)&Bs[(rb + 192) * 72 + cb * 8] = bv3; }

__global__ void __launch_bounds__(512)
fused_mlp_ln_kernel(const ushort_t* __restrict__ A, const ushort_t* __restrict__ W1t,
                    const ushort_t* __restrict__ W2t, const float* __restrict__ ep,
                    float* __restrict__ outF, int M,
                    const ushort_t* __restrict__ Vt2b, const float* __restrict__ kq,
                    ushort_t* __restrict__ vbOut, float* __restrict__ eaOut,
                    unsigned* __restrict__ zrow, float* __restrict__ zea) {
    __shared__ ushort_t Bs[256 * 72];
    __shared__ ushort_t hs[32 * 264];
    __shared__ float s1s[32][4];
    __shared__ float s2s[32][4];
    __shared__ float kqs[1024];         // kq2: [4][256] (dir1 only)
    ushort_t* As = hs;   // alias: As (32*72) only live inside phase-1 k-steps
    int tid = threadIdx.x;
    int w = tid >> 6, lane = tid & 63;
    int l15 = lane & 15, kg = lane >> 4;
    int wr = w >> 2, wc = w & 3;
    int row0 = blockIdx.x * 32;
    bool dir1 = (Vt2b != nullptr);
    if (dir1) { kqs[tid] = kq[tid]; kqs[512 + tid] = kq[512 + tid]; }
    f32x4 acc[4] = {{0.f,0.f,0.f,0.f},{0.f,0.f,0.f,0.f},{0.f,0.f,0.f,0.f},{0.f,0.f,0.f,0.f}};
    int rb = tid >> 3, cb = tid & 7;        // B staging: rows rb(+64..), 16B @ cb
    bool doA = tid < 256;                   // A staging: rows 0..31, 8 thr/row
    int gr = row0 + rb;                     // valid A row iff doA (rb<32)
    uint4 av = {0u,0u,0u,0u};
    uint4 bv0, bv1, bv2, bv3;
    // ---------------- phase 1: h = relu(A @ W1) ----------------
    LOADB4(W1t, 0);
    if (doA && gr < M) av = *(const uint4*)(A + (size_t)gr * 256 + cb * 8);
    for (int k0 = 0; k0 < 256; k0 += 64) {
        WRITEB4();
        if (doA) *(uint4*)&As[rb * 72 + cb * 8] = av;
        __syncthreads();
        if (k0 < 192) {
            LOADB4(W1t, k0 + 64);
            if (doA && gr < M) av = *(const uint4*)(A + (size_t)gr * 256 + (k0 + 64) + cb * 8);
        }
#pragma unroll
        for (int kk = 0; kk < 2; kk++) {
            U4S8 a0_;
            a0_.u = *(const uint4*)&As[(16 * wr + l15) * 72 + kk * 32 + kg * 8];
#pragma unroll
            for (int n = 0; n < 4; n++) {
                U4S8 b; b.u = *(const uint4*)&Bs[(64 * wc + 16 * n + l15) * 72 + kk * 32 + kg * 8];
                acc[n] = __builtin_amdgcn_mfma_f32_16x16x32_bf16(a0_.s, b.s, acc[n], 0, 0, 0);
            }
        }
        __syncthreads();
    }
    // phase-2 prologue loads issued early (overlap with hs store)
    LOADB4(W2t, 0);
    // relu + bf16 into hs (As region dead: every wave passed the last barrier)
#pragma unroll
    for (int n = 0; n < 4; n++) {
#pragma unroll
        for (int rr = 0; rr < 4; rr++) {
            int br = 16 * wr + kg * 4 + rr;
            hs[br * 264 + 64 * wc + 16 * n + l15] = bfbits(fmaxf(acc[n][rr], 0.f));
            acc[n][rr] = 0.f;
        }
    }
    __syncthreads();
    // ---------------- phase 2: y = hs @ W2 ----------------
    for (int k0 = 0; k0 < 256; k0 += 64) {
        WRITEB4();
        __syncthreads();
        if (k0 < 192) LOADB4(W2t, k0 + 64);
#pragma unroll
        for (int kk = 0; kk < 2; kk++) {
            U4S8 a0_;
            a0_.u = *(const uint4*)&hs[(16 * wr + l15) * 264 + k0 + kk * 32 + kg * 8];
#pragma unroll
            for (int n = 0; n < 4; n++) {
                U4S8 b; b.u = *(const uint4*)&Bs[(64 * wc + 16 * n + l15) * 72 + kk * 32 + kg * 8];
                acc[n] = __builtin_amdgcn_mfma_f32_16x16x32_bf16(a0_.s, b.s, acc[n], 0, 0, 0);
            }
        }
        __syncthreads();
    }
    // ---------------- epilogue: y = A + relu(acc); LN1; relu; store --------
    float ym[4][4];
#pragma unroll
    for (int rr = 0; rr < 4; rr++) {
        int br = 16 * wr + kg * 4 + rr;
        int grow = row0 + br;
        float ls1 = 0.f;
#pragma unroll
        for (int n = 0; n < 4; n++) {
            int col = 64 * wc + 16 * n + l15;
            float xv = 0.f;
            if (grow < M) xv = blo((unsigned)A[(size_t)grow * 256 + col]);
            float yv = xv + fmaxf(acc[n][rr], 0.f);
            ym[n][rr] = yv;
            ls1 += yv;
        }
#pragma unroll
        for (int msk = 1; msk < 16; msk <<= 1) ls1 += __shfl_xor(ls1, msk);
        if (l15 == 0) s1s[br][wc] = ls1;
    }
    __syncthreads();
    float mean_[4];
#pragma unroll
    for (int rr = 0; rr < 4; rr++) {
        int br = 16 * wr + kg * 4 + rr;
        float mn = (s1s[br][0] + s1s[br][1] + s1s[br][2] + s1s[br][3]) * (1.f / 256.f);
        mean_[rr] = mn;
        float ls2 = 0.f;
#pragma unroll
        for (int n = 0; n < 4; n++) {
            float d = ym[n][rr] - mn;
            ls2 += d * d;
        }
#pragma unroll
        for (int msk = 1; msk < 16; msk <<= 1) ls2 += __shfl_xor(ls2, msk);
        if (l15 == 0) s2s[br][wc] = ls2;
    }
    __syncthreads();
#pragma unroll
    for (int rr = 0; rr < 4; rr++) {
        int br = 16 * wr + kg * 4 + rr;
        int grow = row0 + br;
        float var = (s2s[br][0] + s2s[br][1] + s2s[br][2] + s2s[br][3]) * (1.f / 256.f);
        float rs = rsqrtf(var + LN_EPS_C);
#pragma unroll
        for (int n = 0; n < 4; n++) {
            int col = 64 * wc + 16 * n + l15;
            float rv = (ym[n][rr] - mean_[rr]) * rs * ep[col] + ep[256 + col];
            rv = fmaxf(rv, 0.f);
            if (grow < M) outF[(size_t)grow * 256 + col] = rv;
            if (dir1) hs[br * 264 + col] = bfbits(rv);
        }
    }
    if (!dir1) return;
    // phase 3 accumulates fresh (r2 lesson) + prologue loads issued early
#pragma unroll
    for (int n = 0; n < 4; n++)
#pragma unroll
        for (int rr = 0; rr < 4; rr++) acc[n][rr] = 0.f;
    LOADB4(Vt2b, 0);
    __syncthreads();
    // ---- dir-2 dummy zeroing (attn1 already consumed ea/vb) ----
    if (blockIdx.x == 0) {
        if (tid < 128) zrow[tid] = 0u;
        else if (tid < 132) zea[tid - 128] = 0.f;
    }
    // ---- mini-expalpha dir2: ea = exp(x1 . kq2), 16 threads/row from hs ----
    {
        int rrow = tid >> 4, rch = tid & 15;
        float h0 = 0.f, h1 = 0.f, h2 = 0.f, h3 = 0.f;
#pragma unroll
        for (int q = 0; q < 2; q++) {
            uint4 xv = *(const uint4*)&hs[rrow * 264 + rch * 16 + q * 8];
            const unsigned* uw = (const unsigned*)&xv;
#pragma unroll
            for (int jj = 0; jj < 4; jj++) {
                float xl = blo(uw[jj]), xh = bhi(uw[jj]);
                int c = rch * 16 + q * 8 + jj * 2;
                h0 += xl * kqs[c]       + xh * kqs[c + 1];
                h1 += xl * kqs[256 + c] + xh * kqs[256 + c + 1];
                h2 += xl * kqs[512 + c] + xh * kqs[512 + c + 1];
                h3 += xl * kqs[768 + c] + xh * kqs[768 + c + 1];
            }
        }
#pragma unroll
        for (int msk = 1; msk < 16; msk <<= 1) {
            h0 += __shfl_xor(h0, msk); h1 += __shfl_xor(h1, msk);
            h2 += __shfl_xor(h2, msk); h3 += __shfl_xor(h3, msk);
        }
        int grow = row0 + rrow;
        if (rch == 0 && grow < M) {
            float4 o;
            o.x = __expf(h0); o.y = __expf(h1); o.z = __expf(h2); o.w = __expf(h3);
            *(float4*)(eaOut + (size_t)grow * 4) = o;
        }
    }
    // ---------------- phase 3: vb = hs(x1) @ Vt2b ----------------
    for (int k0 = 0; k0 < 256; k0 += 64) {
        WRITEB4();
        __syncthreads();
        if (k0 < 192) LOADB4(Vt2b, k0 + 64);
#pragma unroll
        for (int kk = 0; kk < 2; kk++) {
            U4S8 a0_;
            a0_.u = *(const uint4*)&hs[(16 * wr + l15) * 264 + k0 + kk * 32 + kg * 8];
#pragma unroll
            for (int n = 0; n < 4; n++) {
                U4S8 b; b.u = *(const uint4*)&Bs[(64 * wc + 16 * n + l15) * 72 + kk * 32 + kg * 8];
                acc[n] = __builtin_amdgcn_mfma_f32_16x16x32_bf16(a0_.s, b.s, acc[n], 0, 0, 0);
            }
        }
        __syncthreads();
    }
#pragma unroll
    for (int n = 0; n < 4; n++) {
#pragma unroll
        for (int rr = 0; rr < 4; rr++) {
            int row = row0 + 16 * wr + kg * 4 + rr;
            if (row < M)
                vbOut[(size_t)row * 256 + 64 * wc + 16 * n + l15] = bfbits(acc[n][rr]);
        }
    }
}

// ---------------------------------------------------------------------------
// Attention + LN0: one wave per target, 4 ch/lane, byte-offset addressing,
// 2-bank 4+4 pipeline.  Pad slots clamped to dummyIdx in-register (r6).
// ---------------------------------------------------------------------------
#define DECL_BANKD(B) float e##B##0, e##B##1, e##B##2, e##B##3; \
                      uint2 u##B##0, u##B##1, u##B##2, u##B##3;
#define ISSUED1(B, n, sl) { \
    int _i = ((sl) < cnt) ? __shfl(myidx, (sl)) : dummyIdx; \
    int _o = _i << 9; \
    u##B##n = *(const uint2*)(vbL + _o); \
    e##B##n = *(const float*)(eaL + (_o >> 5)); }
#define ISSUED4(B, base) ISSUED1(B,0,(base)) ISSUED1(B,1,(base)+1) ISSUED1(B,2,(base)+2) ISSUED1(B,3,(base)+3)
#define EATD1(B, n) { \
    float wgt = e##B##n; \
    den += wgt; \
    a0 += wgt * blo(u##B##n.x); a1 += wgt * bhi(u##B##n.x); \
    a2 += wgt * blo(u##B##n.y); a3 += wgt * bhi(u##B##n.y); }
#define EATD4(B) EATD1(B,0) EATD1(B,1) EATD1(B,2) EATD1(B,3)

__global__ void __launch_bounds__(256)
attn_ln_kernel(const int* __restrict__ cnts, const ushort_t* __restrict__ scsr,
               const char* __restrict__ eaB, const char* __restrict__ vbB,
               const float* __restrict__ qgb, uint2* __restrict__ xlnbf2,
               int dummyIdx) {
    int wid = (blockIdx.x << 2) + (threadIdx.x >> 6);   // grid = nT/4 exact
    int lane = threadIdx.x & 63;
    const char* vbL = vbB + (lane << 3);
    const char* eaL = eaB + ((lane >> 4) << 2);
    int cnt = cnts[wid];
    if (cnt > CSR_STRIDE) cnt = CSR_STRIDE;
    int myidx = (int)scsr[(wid << 6) + lane];
    float a0 = 0.f, a1 = 0.f, a2 = 0.f, a3 = 0.f, den = 0.f;
    int kr = (cnt + 3) & ~3;
    DECL_BANKD(A)
    DECL_BANKD(B)
    if (kr > 0) { ISSUED4(A, 0) }
    for (int k = 0; k < kr; k += 8) {
        int kb = k + 4;
        bool hasB = kb < kr;
        if (hasB) { ISSUED4(B, kb) }
        EATD4(A)
        int ka = k + 8;
        if (ka < kr) { ISSUED4(A, ka) }
        if (hasB) { EATD4(B) }
    }
    float inv = (den > 0.f) ? (1.f / den) : 0.f;
    int c0i = lane << 2;
    float o0 = a0 * inv + qgb[c0i];
    float o1 = a1 * inv + qgb[c0i + 1];
    float o2 = a2 * inv + qgb[c0i + 2];
    float o3 = a3 * inv + qgb[c0i + 3];
    float part = o0 + o1 + o2 + o3;
#pragma unroll
    for (int m = 32; m; m >>= 1) part += __shfl_xor(part, m);
    float mean = part * (1.f / 256.f);
    float d0 = o0 - mean, d1 = o1 - mean, d2 = o2 - mean, d3 = o3 - mean;
    float p2 = d0 * d0 + d1 * d1 + d2 * d2 + d3 * d3;
#pragma unroll
    for (int m = 32; m; m >>= 1) p2 += __shfl_xor(p2, m);
    float rs = rsqrtf(p2 * (1.f / 256.f) + LN_EPS_C);
    float r0 = d0 * rs * qgb[256 + c0i] + qgb[512 + c0i];
    float r1 = d1 * rs * qgb[256 + c0i + 1] + qgb[512 + c0i + 1];
    float r2 = d2 * rs * qgb[256 + c0i + 2] + qgb[512 + c0i + 2];
    float r3 = d3 * rs * qgb[256 + c0i + 3] + qgb[512 + c0i + 3];
    uint2 outw;
    outw.x = ((unsigned)bfbits(r1) << 16) | bfbits(r0);
    outw.y = ((unsigned)bfbits(r3) << 16) | bfbits(r2);
    xlnbf2[(size_t)wid * 64 + lane] = outw;
}

// ---------------------------------------------------------------------------
// Workspace byte offsets (layout unchanged; KQ1/VT1B regions now unused)
// ---------------------------------------------------------------------------
#define OFF_KQ2   2048
#define OFF_QGB1  6144
#define OFF_EP1   9216
#define OFF_QGB2  11264
#define OFF_EP2   14336
#define OFF_EA    16384      // 100004 floats
#define OFF_VT2B  482048
#define OFF_W1TA  613120
#define OFF_W2TA  744192
#define OFF_W1TB  875264
#define OFF_W2TB  1006336
#define OFF_VB    1137408    // 25001 rows x 512 B
#define OFF_XLNBF 13937920
#define OFF_FLAGS 45937920
#define OFF_FILLH 45937952
#define OFF_FILLN 45987952
#define OFF_SCSRH 46087952
#define OFF_SCSRN 47687952

extern "C" void kernel_launch(void* const* d_in, const int* in_sizes, int n_in,
                              void* d_out, int out_size, void* d_ws, size_t ws_size,
                              hipStream_t stream) {
    const void* x0        = d_in[0];
    const void* node_idx  = d_in[1];
    const void* hedge_idx = d_in[2];
    const void* v2e_K  = d_in[4];
    const void* v2e_Q  = d_in[5];
    const void* v2e_V  = d_in[6];
    const void* v2e_W1 = d_in[7];
    const void* v2e_W2 = d_in[8];
    const void* v2e_ln0_g = d_in[9];
    const void* v2e_ln0_b = d_in[10];
    const void* v2e_ln1_g = d_in[11];
    const void* v2e_ln1_b = d_in[12];
    const void* e2v_K  = d_in[13];
    const void* e2v_Q  = d_in[14];
    const void* e2v_V  = d_in[15];
    const void* e2v_W1 = d_in[16];
    const void* e2v_W2 = d_in[17];
    const void* e2v_ln0_g = d_in[18];
    const void* e2v_ln0_b = d_in[19];
    const void* e2v_ln1_g = d_in[20];
    const void* e2v_ln1_b = d_in[21];

    float* out = (float*)d_out;
    float* out_x0 = out;
    float* out_x1 = out + (size_t)N_NODES_C * HID_C;

    char* base = (char*)d_ws;
    float*    kq2   = (float*)(base + OFF_KQ2);
    float*    qgb1  = (float*)(base + OFF_QGB1);
    float*    ep1   = (float*)(base + OFF_EP1);
    float*    qgb2  = (float*)(base + OFF_QGB2);
    float*    ep2   = (float*)(base + OFF_EP2);
    float*    ea    = (float*)(base + OFF_EA);
    ushort_t* Vt2b  = (ushort_t*)(base + OFF_VT2B);
    ushort_t* W1tA  = (ushort_t*)(base + OFF_W1TA);
    ushort_t* W2tA  = (ushort_t*)(base + OFF_W2TA);
    ushort_t* W1tB  = (ushort_t*)(base + OFF_W1TB);
    ushort_t* W2tB  = (ushort_t*)(base + OFF_W2TB);
    ushort_t* vb    = (ushort_t*)(base + OFF_VB);
    ushort_t* xlnbf = (ushort_t*)(base + OFF_XLNBF);
    int*      flags = (int*)(base + OFF_FLAGS);
    int*      fill_h = (int*)(base + OFF_FILLH);
    int*      fill_n = (int*)(base + OFF_FILLN);
    ushort_t* scsr_h = (ushort_t*)(base + OFF_SCSRH);
    ushort_t* scsr_n = (ushort_t*)(base + OFF_SCSRN);

    init_kernel<<<INIT_GRID, 256, 0, stream>>>(
        (const unsigned*)x0, (const unsigned*)node_idx, flags,
        (unsigned*)fill_h, (unsigned*)vb, (unsigned*)ea);

    mega_kernel<<<MEGA_GRID, 256, 0, stream>>>(
        node_idx, hedge_idx, fill_h, fill_n, scsr_h, scsr_n,
        x0, vb, ea,
        v2e_K, v2e_Q, v2e_V, e2v_K, e2v_Q, e2v_V,
        v2e_W1, v2e_W2, e2v_W1, e2v_W2,
        v2e_ln0_g, v2e_ln0_b, v2e_ln1_g, v2e_ln1_b,
        e2v_ln0_g, e2v_ln0_b, e2v_ln1_g, e2v_ln1_b,
        flags, kq2, Vt2b, W1tA, W2tA, W1tB, W2tB,
        qgb1, ep1, qgb2, ep2);

    // ----- block 1: vertices -> hyperedges -----
    attn_ln_kernel<<<N_HEDGES_C / 4, 256, 0, stream>>>(
        fill_h, scsr_h, (const char*)ea, (const char*)vb, qgb1, (uint2*)xlnbf,
        25000);
    fused_mlp_ln_kernel<<<(N_HEDGES_C + 31) / 32, 512, 0, stream>>>(
        xlnbf, W1tA, W2tA, ep1, out_x1, N_HEDGES_C,
        Vt2b, kq2, vb, ea,
        (unsigned*)vb + 12500 * 128, ea + 50000);

    // ----- block 2: hyperedges -> vertices -----
    attn_ln_kernel<<<N_NODES_C / 4, 256, 0, stream>>>(
        fill_n, scsr_n, (const char*)ea, (const char*)vb, qgb2, (uint2*)xlnbf,
        12500);
    fused_mlp_ln_kernel<<<(N_NODES_C + 31) / 32, 512, 0, stream>>>(
        xlnbf, W1tB, W2tB, ep2, out_x0, N_NODES_C,
        nullptr, nullptr, nullptr, nullptr, nullptr, nullptr);
}

// Round 8
// 184.663 us; speedup vs baseline: 1.3095x; 1.3095x over previous
//
#include <hip/hip_runtime.h>
#include <hip/hip_bf16.h>

#define N_NODES_C 25000
#define N_HEDGES_C 12500
#define NNZ_C 400000
#define C_IN_C 128
#define HID_C 256
#define LN_EPS_C 1e-5f
#define CSR_STRIDE 64

typedef unsigned short ushort_t;
typedef __attribute__((ext_vector_type(8))) short short8;
typedef __attribute__((ext_vector_type(4))) float f32x4;

union U4S8 { uint4 u; short8 s; };

__device__ __forceinline__ float ldsel(const void* p, size_t i, bool f32) {
    return f32 ? ((const float*)p)[i] : __bfloat162float(((const __hip_bfloat16*)p)[i]);
}
__device__ __forceinline__ int ldidx_nt(const void* p, size_t i, bool i64) {
    // r8: non-temporal edge-list reads — the 8x sliced re-read streams 12.8MB
    // through each XCD's L2 and was evicting the partially-filled scsr lines
    // (r6 counters: WRITE 30.4MB vs 1.75MB live).  nt keeps the stream from
    // claiming L2 residency.
    if (i64) return (int)__builtin_nontemporal_load((const long long*)p + i);
    return __builtin_nontemporal_load((const int*)p + i);
}
__device__ __forceinline__ ushort_t bfbits(float f) {
    union { float f; unsigned u; } v; v.f = f;
    unsigned r = v.u + 0x7FFF + ((v.u >> 16) & 1);
    return (ushort_t)(r >> 16);
}
__device__ __forceinline__ float blo(unsigned u) {
    union { unsigned u; float f; } v; v.u = u << 16; return v.f;
}
__device__ __forceinline__ float bhi(unsigned u) {
    union { unsigned u; float f; } v; v.u = u & 0xFFFF0000u; return v.f;
}

// ---------------------------------------------------------------------------
// init (r6): block 0 = dtype sniff; rest zero counters + vb dummy row + ea
// dummy slots.  attn clamps pad slots, so no scsr dummy-fill needed.
// ---------------------------------------------------------------------------
#define INIT_GRID 148   // 1 + (37500+128+4 -> 37632)/256
__global__ void __launch_bounds__(256)
init_kernel(const unsigned* __restrict__ x0w, const unsigned* __restrict__ idxw,
            int* __restrict__ flags, unsigned* __restrict__ cnts,
            unsigned* __restrict__ vb32, unsigned* __restrict__ ea32) {
    int bid = blockIdx.x;
    if (bid == 0) {
        __shared__ int cnt[2];
        int t = threadIdx.x;
        if (t < 2) cnt[t] = 0;
        __syncthreads();
        int c0 = 0, c1 = 0;
        for (int k = 0; k < 4; k++) {
            unsigned w = x0w[t * 4 + k];
            unsigned elo = (w >> 7) & 0xFF;
            if (elo >= 100 && elo <= 134) c0++;
            if (idxw[2 * (t * 4 + k) + 1] == 0) c1++;
        }
        atomicAdd(&cnt[0], c0);
        atomicAdd(&cnt[1], c1);
        __syncthreads();
        if (t == 0) {
            flags[0] = (cnt[0] < 512) ? 1 : 0;  // 1 => floats are f32
            flags[1] = (cnt[1] >= 512) ? 1 : 0; // 1 => indices are int64
        }
        return;
    }
    int i = (bid - 1) * 256 + threadIdx.x;
    if (i < 37500) { cnts[i] = 0u; return; }
    i -= 37500;
    if (i < 128) { vb32[25000 * 128 + i] = 0u; return; }
    i -= 128;
    if (i < 4) ea32[100000 + i] = 0u;
}

// ---------------------------------------------------------------------------
// prep_fill (r6 structure, proven 183us; r7 mega-merge REVERTED — uniform
// 30KB LDS collapsed fill occupancy 55->24%, dispatch 49->125us.  Lesson:
// only merge block-ranges with compatible LDS/VGPR footprints.)
//  blocks [0, 3128): XCD-sliced padded-CSR fill, r8: nt edge reads.
//  blocks [3128, ..): prep (kq dots, V/W transposes -> bf16, f32 tables).
// ---------------------------------------------------------------------------
#define FILL_CHUNK 1024
#define FILL_NCHUNK ((NNZ_C + FILL_CHUNK - 1) / FILL_CHUNK)   // 391
#define FILL_BLOCKS (8 * FILL_NCHUNK)                         // 3128
#define HSLICE_SZ 1563
#define NSLICE_SZ 3125
#define PREP_TOTAL 364544
#define PREP_BLOCKS ((PREP_TOTAL + 255) / 256)                // 1424
#define PF_GRID (FILL_BLOCKS + PREP_BLOCKS)                   // 4552

__global__ void __launch_bounds__(256)
prep_fill_kernel(const void* __restrict__ node_idx, const void* __restrict__ hedge_idx,
                 int* __restrict__ fill_h, int* __restrict__ fill_n,
                 ushort_t* __restrict__ scsr_h, ushort_t* __restrict__ scsr_n,
                 const void* __restrict__ K1, const void* __restrict__ Q1,
                 const void* __restrict__ V1,
                 const void* __restrict__ K2, const void* __restrict__ Q2,
                 const void* __restrict__ V2,
                 const void* __restrict__ W1a, const void* __restrict__ W2a,
                 const void* __restrict__ W1b, const void* __restrict__ W2b,
                 const void* __restrict__ G0a, const void* __restrict__ B0a,
                 const void* __restrict__ G1a, const void* __restrict__ B1a,
                 const void* __restrict__ G0b, const void* __restrict__ B0b,
                 const void* __restrict__ G1b, const void* __restrict__ B1b,
                 const int* __restrict__ flags,
                 float* __restrict__ kq1, float* __restrict__ kq2,
                 ushort_t* __restrict__ Vt1b, ushort_t* __restrict__ Vt2b,
                 ushort_t* __restrict__ W1tA, ushort_t* __restrict__ W2tA,
                 ushort_t* __restrict__ W1tB, ushort_t* __restrict__ W2tB,
                 float* __restrict__ qgb1, float* __restrict__ ep1,
                 float* __restrict__ qgb2, float* __restrict__ ep2) {
    if (blockIdx.x < FILL_BLOCKS) {
        bool i64 = flags[1] != 0;
        int s = blockIdx.x & 7;
        int chunk = blockIdx.x >> 3;
        int e0 = chunk * FILL_CHUNK;
        int e1 = e0 + FILL_CHUNK; if (e1 > NNZ_C) e1 = NNZ_C;
        int hlo = s * HSLICE_SZ, hhi = hlo + HSLICE_SZ;
        int nlo = s * NSLICE_SZ, nhi = nlo + NSLICE_SZ;
        for (int e = e0 + threadIdx.x; e < e1; e += 256) {
            int nd = ldidx_nt(node_idx, e, i64);
            int he = ldidx_nt(hedge_idx, e, i64);
            if (he >= hlo && he < hhi) {
                int p = atomicAdd(&fill_h[he], 1);
                if (p < CSR_STRIDE) scsr_h[(he << 6) + p] = (ushort_t)nd;
            }
            if (nd >= nlo && nd < nhi) {
                int p = atomicAdd(&fill_n[nd], 1);
                if (p < CSR_STRIDE) scsr_n[(nd << 6) + p] = (ushort_t)he;
            }
        }
        return;
    }
    bool f32 = flags[0] != 0;
    size_t i = (size_t)(blockIdx.x - FILL_BLOCKS) * 256 + threadIdx.x;
    if (i >= PREP_TOTAL) return;
    if (i < 512) {
        int h = (int)(i >> 7), c = (int)(i & 127);
        float s = 0.f;
        for (int d = 0; d < 64; d++)
            s += ldsel(K1, (size_t)(h * 128 + c) * 64 + d, f32) * ldsel(Q1, h * 64 + d, f32);
        kq1[h * 128 + c] = s;
        return;
    }
    i -= 512;
    if (i < 1024) {
        int h = (int)(i >> 8), c = (int)(i & 255);
        float s = 0.f;
        for (int d = 0; d < 64; d++)
            s += ldsel(K2, (size_t)(h * 256 + c) * 64 + d, f32) * ldsel(Q2, h * 64 + d, f32);
        kq2[h * 256 + c] = s;
        return;
    }
    i -= 1024;
    if (i < 32768) {
        int j = (int)(i >> 7), c = (int)(i & 127);
        int h = j >> 6, d = j & 63;
        Vt1b[i] = bfbits(ldsel(V1, (size_t)(h * 128 + c) * 64 + d, f32));
        return;
    }
    i -= 32768;
    if (i < 65536) {
        int j = (int)(i >> 8), c = (int)(i & 255);
        int h = j >> 6, d = j & 63;
        Vt2b[i] = bfbits(ldsel(V2, (size_t)(h * 256 + c) * 64 + d, f32));
        return;
    }
    i -= 65536;
    if (i < 65536) { int n = (int)(i >> 8), k = (int)(i & 255);
        W1tA[i] = bfbits(ldsel(W1a, (size_t)k * 256 + n, f32)); return; }
    i -= 65536;
    if (i < 65536) { int n = (int)(i >> 8), k = (int)(i & 255);
        W2tA[i] = bfbits(ldsel(W2a, (size_t)k * 256 + n, f32)); return; }
    i -= 65536;
    if (i < 65536) { int n = (int)(i >> 8), k = (int)(i & 255);
        W1tB[i] = bfbits(ldsel(W1b, (size_t)k * 256 + n, f32)); return; }
    i -= 65536;
    if (i < 65536) { int n = (int)(i >> 8), k = (int)(i & 255);
        W2tB[i] = bfbits(ldsel(W2b, (size_t)k * 256 + n, f32)); return; }
    i -= 65536;
    {
        int which = (int)(i >> 8);
        int j = (int)(i & 255);
        const void* src; float* dst;
        switch (which) {
            case 0: src = Q1;  dst = qgb1;       break;
            case 1: src = G0a; dst = qgb1 + 256; break;
            case 2: src = B0a; dst = qgb1 + 512; break;
            case 3: src = G1a; dst = ep1;        break;
            case 4: src = B1a; dst = ep1 + 256;  break;
            case 5: src = Q2;  dst = qgb2;       break;
            case 6: src = G0b; dst = qgb2 + 256; break;
            case 7: src = B0b; dst = qgb2 + 512; break;
            case 8: src = G1b; dst = ep2;        break;
            default: src = B1b; dst = ep2 + 256;  break;
        }
        dst[j] = ldsel(src, j, f32);
    }
}

// ---------------------------------------------------------------------------
// gemm_x0 + fused expalpha dir-1 (proven r3/r6, standalone again)
// ---------------------------------------------------------------------------
__global__ void __launch_bounds__(256)
gemm_x0_kernel(const void* __restrict__ x0, const int* __restrict__ flags,
               const ushort_t* __restrict__ Bt, ushort_t* __restrict__ C,
               int M, int K, const float* __restrict__ kq, float* __restrict__ ea) {
    __shared__ ushort_t As[64 * 72];
    __shared__ ushort_t Bs[128 * 72];
    __shared__ float kqs[512];          // kq1: [4][128]
    bool f32 = flags[0] != 0;
    int tid = threadIdx.x;
    int w = tid >> 6, lane = tid & 63;
    int l15 = lane & 15, kg = lane >> 4;
    int wr = w >> 1, wc = w & 1;
    int row0 = blockIdx.x * 64, col0 = blockIdx.y * 128;
    bool doEa = (blockIdx.y == 0);
    kqs[tid] = kq[tid];
    kqs[256 + tid] = kq[256 + tid];
    __syncthreads();
    f32x4 acc[2][4] = {{{0.f,0.f,0.f,0.f},{0.f,0.f,0.f,0.f},{0.f,0.f,0.f,0.f},{0.f,0.f,0.f,0.f}},
                       {{0.f,0.f,0.f,0.f},{0.f,0.f,0.f,0.f},{0.f,0.f,0.f,0.f},{0.f,0.f,0.f,0.f}}};
    float hd[2][4] = {{0.f,0.f,0.f,0.f},{0.f,0.f,0.f,0.f}};
    int r_ = tid >> 3, ch = tid & 7;
    for (int k0 = 0; k0 < K; k0 += 64) {
#pragma unroll
        for (int p = 0; p < 2; p++) {
            int r = p * 32 + r_;
            uint4 av = {0u,0u,0u,0u};
            int gr = row0 + r;
            if (gr < M) {
                float fv[8];
                if (!f32) {
                    av = *(const uint4*)((const ushort_t*)x0 + (size_t)gr * K + k0 + ch * 8);
                    if (doEa) {
                        unsigned* uw = (unsigned*)&av;
#pragma unroll
                        for (int jj = 0; jj < 4; jj++) { fv[2 * jj] = blo(uw[jj]); fv[2 * jj + 1] = bhi(uw[jj]); }
                    }
                } else {
                    const float* ap = (const float*)x0 + (size_t)gr * K + k0 + ch * 8;
                    float4 f0 = *(const float4*)ap;
                    float4 f1 = *(const float4*)(ap + 4);
                    av.x = (unsigned)bfbits(f0.x) | ((unsigned)bfbits(f0.y) << 16);
                    av.y = (unsigned)bfbits(f0.z) | ((unsigned)bfbits(f0.w) << 16);
                    av.z = (unsigned)bfbits(f1.x) | ((unsigned)bfbits(f1.y) << 16);
                    av.w = (unsigned)bfbits(f1.z) | ((unsigned)bfbits(f1.w) << 16);
                    if (doEa) {
                        fv[0] = f0.x; fv[1] = f0.y; fv[2] = f0.z; fv[3] = f0.w;
                        fv[4] = f1.x; fv[5] = f1.y; fv[6] = f1.z; fv[7] = f1.w;
                    }
                }
                if (doEa) {
                    int c = k0 + ch * 8;
#pragma unroll
                    for (int h = 0; h < 4; h++) {
                        float s = 0.f;
#pragma unroll
                        for (int j = 0; j < 8; j++) s += fv[j] * kqs[h * 128 + c + j];
                        hd[p][h] += s;
                    }
                }
            }
            *(uint4*)&As[r * 72 + ch * 8] = av;
        }
#pragma unroll
        for (int p = 0; p < 4; p++) {
            int i = p * 256 + tid;
            int r2 = i >> 3, c2 = i & 7;
            uint4 bv = *(const uint4*)(Bt + (size_t)(col0 + r2) * K + k0 + c2 * 8);
            *(uint4*)&Bs[r2 * 72 + c2 * 8] = bv;
        }
        __syncthreads();
#pragma unroll
        for (int kk = 0; kk < 2; kk++) {
            U4S8 a0_, a1_;
            a0_.u = *(const uint4*)&As[(32 * wr + l15) * 72 + kk * 32 + kg * 8];
            a1_.u = *(const uint4*)&As[(32 * wr + 16 + l15) * 72 + kk * 32 + kg * 8];
#pragma unroll
            for (int n = 0; n < 4; n++) {
                U4S8 b; b.u = *(const uint4*)&Bs[(64 * wc + 16 * n + l15) * 72 + kk * 32 + kg * 8];
                acc[0][n] = __builtin_amdgcn_mfma_f32_16x16x32_bf16(a0_.s, b.s, acc[0][n], 0, 0, 0);
                acc[1][n] = __builtin_amdgcn_mfma_f32_16x16x32_bf16(a1_.s, b.s, acc[1][n], 0, 0, 0);
            }
        }
        __syncthreads();
    }
#pragma unroll
    for (int m = 0; m < 2; m++) {
#pragma unroll
        for (int n = 0; n < 4; n++) {
#pragma unroll
            for (int rr = 0; rr < 4; rr++) {
                int row = row0 + 32 * wr + 16 * m + kg * 4 + rr;
                if (row < M)
                    C[(size_t)row * 256 + col0 + 64 * wc + 16 * n + l15] = bfbits(acc[m][n][rr]);
            }
        }
    }
    if (doEa) {
#pragma unroll
        for (int p = 0; p < 2; p++) {
#pragma unroll
            for (int msk = 1; msk < 8; msk <<= 1) {
                hd[p][0] += __shfl_xor(hd[p][0], msk);
                hd[p][1] += __shfl_xor(hd[p][1], msk);
                hd[p][2] += __shfl_xor(hd[p][2], msk);
                hd[p][3] += __shfl_xor(hd[p][3], msk);
            }
            if (ch == 0) {
                int row = row0 + p * 32 + r_;
                if (row < M) {
                    float4 o;
                    o.x = __expf(hd[p][0]); o.y = __expf(hd[p][1]);
                    o.z = __expf(hd[p][2]); o.w = __expf(hd[p][3]);
                    *(float4*)(ea + (size_t)row * 4) = o;
                }
            }
        }
    }
}

// ---------------------------------------------------------------------------
// Fused MLP + LN1 (+ dir-1 extras) — r4 retile: 32 rows/block,
// register-prefetch staging.  8 waves: wave w computes rows 16*(w>>2)..+16,
// cols 64*(w&3)..+64 (acc[4]).  LDS ~59K -> 2 blocks/CU.
// ---------------------------------------------------------------------------
#define LOADB4(SRC, KO) { \
    bv0 = *(const uint4*)((SRC) + (size_t)rb * 256 + (KO) + cb * 8); \
    bv1 = *(const uint4*)((SRC) + (size_t)(rb + 64) * 256 + (KO) + cb * 8); \
    bv2 = *(const uint4*)((SRC) + (size_t)(rb + 128) * 256 + (KO) + cb * 8); \
    bv3 = *(const uint4*)((SRC) + (size_t)(rb + 192) * 256 + (KO) + cb * 8); }
#define WRITEB4() { \
    *(uint4*)&Bs[rb * 72 + cb * 8] = bv0; \
    *(uint4*)&Bs[(rb + 64) * 72 + cb * 8] = bv1; \
    *(uint4*)&Bs[(rb + 128) * 72 + cb * 8] = bv2; \
    *(uint4*)&Bs[(rb + 192) * 72 + cb * 8] = bv3; }

__global__ void __launch_bounds__(512)
fused_mlp_ln_kernel(const ushort_t* __restrict__ A, const ushort_t* __restrict__ W1t,
                    const ushort_t* __restrict__ W2t, const float* __restrict__ ep,
                    float* __restrict__ outF, int M,
                    const ushort_t* __restrict__ Vt2b, const float* __restrict__ kq,
                    ushort_t* __restrict__ vbOut, float* __restrict__ eaOut,
                    unsigned* __restrict__ zrow, float* __restrict__ zea) {
    __shared__ ushort_t Bs[256 * 72];
    __shared__ ushort_t hs[32 * 264];
    __shared__ float s1s[32][4];
    __shared__ float s2s[32][4];
    __shared__ float kqs[1024];         // kq2: [4][256] (dir1 only)
    ushort_t* As = hs;   // alias: As (32*72) only live inside phase-1 k-steps
    int tid = threadIdx.x;
    int w = tid >> 6, lane = tid & 63;
    int l15 = lane & 15, kg = lane >> 4;
    int wr = w >> 2, wc = w & 3;
    int row0 = blockIdx.x * 32;
    bool dir1 = (Vt2b != nullptr);
    if (dir1) { kqs[tid] = kq[tid]; kqs[512 + tid] = kq[512 + tid]; }
    f32x4 acc[4] = {{0.f,0.f,0.f,0.f},{0.f,0.f,0.f,0.f},{0.f,0.f,0.f,0.f},{0.f,0.f,0.f,0.f}};
    int rb = tid >> 3, cb = tid & 7;        // B staging: rows rb(+64..), 16B @ cb
    bool doA = tid < 256;                   // A staging: rows 0..31, 8 thr/row
    int gr = row0 + rb;                     // valid A row iff doA (rb<32)
    uint4 av = {0u,0u,0u,0u};
    uint4 bv0, bv1, bv2, bv3;
    // ---------------- phase 1: h = relu(A @ W1) ----------------
    LOADB4(W1t, 0);
    if (doA && gr < M) av = *(const uint4*)(A + (size_t)gr * 256 + cb * 8);
    for (int k0 = 0; k0 < 256; k0 += 64) {
        WRITEB4();
        if (doA) *(uint4*)&As[rb * 72 + cb * 8] = av;
        __syncthreads();
        if (k0 < 192) {
            LOADB4(W1t, k0 + 64);
            if (doA && gr < M) av = *(const uint4*)(A + (size_t)gr * 256 + (k0 + 64) + cb * 8);
        }
#pragma unroll
        for (int kk = 0; kk < 2; kk++) {
            U4S8 a0_;
            a0_.u = *(const uint4*)&As[(16 * wr + l15) * 72 + kk * 32 + kg * 8];
#pragma unroll
            for (int n = 0; n < 4; n++) {
                U4S8 b; b.u = *(const uint4*)&Bs[(64 * wc + 16 * n + l15) * 72 + kk * 32 + kg * 8];
                acc[n] = __builtin_amdgcn_mfma_f32_16x16x32_bf16(a0_.s, b.s, acc[n], 0, 0, 0);
            }
        }
        __syncthreads();
    }
    // phase-2 prologue loads issued early (overlap with hs store)
    LOADB4(W2t, 0);
    // relu + bf16 into hs (As region dead: every wave passed the last barrier)
#pragma unroll
    for (int n = 0; n < 4; n++) {
#pragma unroll
        for (int rr = 0; rr < 4; rr++) {
            int br = 16 * wr + kg * 4 + rr;
            hs[br * 264 + 64 * wc + 16 * n + l15] = bfbits(fmaxf(acc[n][rr], 0.f));
            acc[n][rr] = 0.f;
        }
    }
    __syncthreads();
    // ---------------- phase 2: y = hs @ W2 ----------------
    for (int k0 = 0; k0 < 256; k0 += 64) {
        WRITEB4();
        __syncthreads();
        if (k0 < 192) LOADB4(W2t, k0 + 64);
#pragma unroll
        for (int kk = 0; kk < 2; kk++) {
            U4S8 a0_;
            a0_.u = *(const uint4*)&hs[(16 * wr + l15) * 264 + k0 + kk * 32 + kg * 8];
#pragma unroll
            for (int n = 0; n < 4; n++) {
                U4S8 b; b.u = *(const uint4*)&Bs[(64 * wc + 16 * n + l15) * 72 + kk * 32 + kg * 8];
                acc[n] = __builtin_amdgcn_mfma_f32_16x16x32_bf16(a0_.s, b.s, acc[n], 0, 0, 0);
            }
        }
        __syncthreads();
    }
    // ---------------- epilogue: y = A + relu(acc); LN1; relu; store --------
    float ym[4][4];
#pragma unroll
    for (int rr = 0; rr < 4; rr++) {
        int br = 16 * wr + kg * 4 + rr;
        int grow = row0 + br;
        float ls1 = 0.f;
#pragma unroll
        for (int n = 0; n < 4; n++) {
            int col = 64 * wc + 16 * n + l15;
            float xv = 0.f;
            if (grow < M) xv = blo((unsigned)A[(size_t)grow * 256 + col]);
            float yv = xv + fmaxf(acc[n][rr], 0.f);
            ym[n][rr] = yv;
            ls1 += yv;
        }
#pragma unroll
        for (int msk = 1; msk < 16; msk <<= 1) ls1 += __shfl_xor(ls1, msk);
        if (l15 == 0) s1s[br][wc] = ls1;
    }
    __syncthreads();
    float mean_[4];
#pragma unroll
    for (int rr = 0; rr < 4; rr++) {
        int br = 16 * wr + kg * 4 + rr;
        float mn = (s1s[br][0] + s1s[br][1] + s1s[br][2] + s1s[br][3]) * (1.f / 256.f);
        mean_[rr] = mn;
        float ls2 = 0.f;
#pragma unroll
        for (int n = 0; n < 4; n++) {
            float d = ym[n][rr] - mn;
            ls2 += d * d;
        }
#pragma unroll
        for (int msk = 1; msk < 16; msk <<= 1) ls2 += __shfl_xor(ls2, msk);
        if (l15 == 0) s2s[br][wc] = ls2;
    }
    __syncthreads();
#pragma unroll
    for (int rr = 0; rr < 4; rr++) {
        int br = 16 * wr + kg * 4 + rr;
        int grow = row0 + br;
        float var = (s2s[br][0] + s2s[br][1] + s2s[br][2] + s2s[br][3]) * (1.f / 256.f);
        float rs = rsqrtf(var + LN_EPS_C);
#pragma unroll
        for (int n = 0; n < 4; n++) {
            int col = 64 * wc + 16 * n + l15;
            float rv = (ym[n][rr] - mean_[rr]) * rs * ep[col] + ep[256 + col];
            rv = fmaxf(rv, 0.f);
            if (grow < M) outF[(size_t)grow * 256 + col] = rv;
            if (dir1) hs[br * 264 + col] = bfbits(rv);
        }
    }
    if (!dir1) return;
    // phase 3 accumulates fresh (r2 lesson) + prologue loads issued early
#pragma unroll
    for (int n = 0; n < 4; n++)
#pragma unroll
        for (int rr = 0; rr < 4; rr++) acc[n][rr] = 0.f;
    LOADB4(Vt2b, 0);
    __syncthreads();
    // ---- dir-2 dummy zeroing (attn1 already consumed ea/vb) ----
    if (blockIdx.x == 0) {
        if (tid < 128) zrow[tid] = 0u;
        else if (tid < 132) zea[tid - 128] = 0.f;
    }
    // ---- mini-expalpha dir2: ea = exp(x1 . kq2), 16 threads/row from hs ----
    {
        int rrow = tid >> 4, rch = tid & 15;
        float h0 = 0.f, h1 = 0.f, h2 = 0.f, h3 = 0.f;
#pragma unroll
        for (int q = 0; q < 2; q++) {
            uint4 xv = *(const uint4*)&hs[rrow * 264 + rch * 16 + q * 8];
            const unsigned* uw = (const unsigned*)&xv;
#pragma unroll
            for (int jj = 0; jj < 4; jj++) {
                float xl = blo(uw[jj]), xh = bhi(uw[jj]);
                int c = rch * 16 + q * 8 + jj * 2;
                h0 += xl * kqs[c]       + xh * kqs[c + 1];
                h1 += xl * kqs[256 + c] + xh * kqs[256 + c + 1];
                h2 += xl * kqs[512 + c] + xh * kqs[512 + c + 1];
                h3 += xl * kqs[768 + c] + xh * kqs[768 + c + 1];
            }
        }
#pragma unroll
        for (int msk = 1; msk < 16; msk <<= 1) {
            h0 += __shfl_xor(h0, msk); h1 += __shfl_xor(h1, msk);
            h2 += __shfl_xor(h2, msk); h3 += __shfl_xor(h3, msk);
        }
        int grow = row0 + rrow;
        if (rch == 0 && grow < M) {
            float4 o;
            o.x = __expf(h0); o.y = __expf(h1); o.z = __expf(h2); o.w = __expf(h3);
            *(float4*)(eaOut + (size_t)grow * 4) = o;
        }
    }
    // ---------------- phase 3: vb = hs(x1) @ Vt2b ----------------
    for (int k0 = 0; k0 < 256; k0 += 64) {
        WRITEB4();
        __syncthreads();
        if (k0 < 192) LOADB4(Vt2b, k0 + 64);
#pragma unroll
        for (int kk = 0; kk < 2; kk++) {
            U4S8 a0_;
            a0_.u = *(const uint4*)&hs[(16 * wr + l15) * 264 + k0 + kk * 32 + kg * 8];
#pragma unroll
            for (int n = 0; n < 4; n++) {
                U4S8 b; b.u = *(const uint4*)&Bs[(64 * wc + 16 * n + l15) * 72 + kk * 32 + kg * 8];
                acc[n] = __builtin_amdgcn_mfma_f32_16x16x32_bf16(a0_.s, b.s, acc[n], 0, 0, 0);
            }
        }
        __syncthreads();
    }
#pragma unroll
    for (int n = 0; n < 4; n++) {
#pragma unroll
        for (int rr = 0; rr < 4; rr++) {
            int row = row0 + 16 * wr + kg * 4 + rr;
            if (row < M)
                vbOut[(size_t)row * 256 + 64 * wc + 16 * n + l15] = bfbits(acc[n][rr]);
        }
    }
}

// ---------------------------------------------------------------------------
// Attention + LN0: one wave per target, 4 ch/lane, byte-offset addressing,
// 2-bank 4+4 pipeline.  Pad slots clamped to dummyIdx in-register (r6).
// ---------------------------------------------------------------------------
#define DECL_BANKD(B) float e##B##0, e##B##1, e##B##2, e##B##3; \
                      uint2 u##B##0, u##B##1, u##B##2, u##B##3;
#define ISSUED1(B, n, sl) { \
    int _i = ((sl) < cnt) ? __shfl(myidx, (sl)) : dummyIdx; \
    int _o = _i << 9; \
    u##B##n = *(const uint2*)(vbL + _o); \
    e##B##n = *(const float*)(eaL + (_o >> 5)); }
#define ISSUED4(B, base) ISSUED1(B,0,(base)) ISSUED1(B,1,(base)+1) ISSUED1(B,2,(base)+2) ISSUED1(B,3,(base)+3)
#define EATD1(B, n) { \
    float wgt = e##B##n; \
    den += wgt; \
    a0 += wgt * blo(u##B##n.x); a1 += wgt * bhi(u##B##n.x); \
    a2 += wgt * blo(u##B##n.y); a3 += wgt * bhi(u##B##n.y); }
#define EATD4(B) EATD1(B,0) EATD1(B,1) EATD1(B,2) EATD1(B,3)

__global__ void __launch_bounds__(256)
attn_ln_kernel(const int* __restrict__ cnts, const ushort_t* __restrict__ scsr,
               const char* __restrict__ eaB, const char* __restrict__ vbB,
               const float* __restrict__ qgb, uint2* __restrict__ xlnbf2,
               int dummyIdx) {
    int wid = (blockIdx.x << 2) + (threadIdx.x >> 6);   // grid = nT/4 exact
    int lane = threadIdx.x & 63;
    const char* vbL = vbB + (lane << 3);
    const char* eaL = eaB + ((lane >> 4) << 2);
    int cnt = cnts[wid];
    if (cnt > CSR_STRIDE) cnt = CSR_STRIDE;
    int myidx = (int)scsr[(wid << 6) + lane];
    float a0 = 0.f, a1 = 0.f, a2 = 0.f, a3 = 0.f, den = 0.f;
    int kr = (cnt + 3) & ~3;
    DECL_BANKD(A)
    DECL_BANKD(B)
    if (kr > 0) { ISSUED4(A, 0) }
    for (int k = 0; k < kr; k += 8) {
        int kb = k + 4;
        bool hasB = kb < kr;
        if (hasB) { ISSUED4(B, kb) }
        EATD4(A)
        int ka = k + 8;
        if (ka < kr) { ISSUED4(A, ka) }
        if (hasB) { EATD4(B) }
    }
    float inv = (den > 0.f) ? (1.f / den) : 0.f;
    int c0i = lane << 2;
    float o0 = a0 * inv + qgb[c0i];
    float o1 = a1 * inv + qgb[c0i + 1];
    float o2 = a2 * inv + qgb[c0i + 2];
    float o3 = a3 * inv + qgb[c0i + 3];
    float part = o0 + o1 + o2 + o3;
#pragma unroll
    for (int m = 32; m; m >>= 1) part += __shfl_xor(part, m);
    float mean = part * (1.f / 256.f);
    float d0 = o0 - mean, d1 = o1 - mean, d2 = o2 - mean, d3 = o3 - mean;
    float p2 = d0 * d0 + d1 * d1 + d2 * d2 + d3 * d3;
#pragma unroll
    for (int m = 32; m; m >>= 1) p2 += __shfl_xor(p2, m);
    float rs = rsqrtf(p2 * (1.f / 256.f) + LN_EPS_C);
    float r0 = d0 * rs * qgb[256 + c0i] + qgb[512 + c0i];
    float r1 = d1 * rs * qgb[256 + c0i + 1] + qgb[512 + c0i + 1];
    float r2 = d2 * rs * qgb[256 + c0i + 2] + qgb[512 + c0i + 2];
    float r3 = d3 * rs * qgb[256 + c0i + 3] + qgb[512 + c0i + 3];
    uint2 outw;
    outw.x = ((unsigned)bfbits(r1) << 16) | bfbits(r0);
    outw.y = ((unsigned)bfbits(r3) << 16) | bfbits(r2);
    xlnbf2[(size_t)wid * 64 + lane] = outw;
}

// ---------------------------------------------------------------------------
// Workspace byte offsets (layout unchanged)
// ---------------------------------------------------------------------------
#define OFF_KQ1   0
#define OFF_KQ2   2048
#define OFF_QGB1  6144
#define OFF_EP1   9216
#define OFF_QGB2  11264
#define OFF_EP2   14336
#define OFF_EA    16384      // 100004 floats
#define OFF_VT1B  416512
#define OFF_VT2B  482048
#define OFF_W1TA  613120
#define OFF_W2TA  744192
#define OFF_W1TB  875264
#define OFF_W2TB  1006336
#define OFF_VB    1137408    // 25001 rows x 512 B
#define OFF_XLNBF 13937920
#define OFF_FLAGS 45937920
#define OFF_FILLH 45937952
#define OFF_FILLN 45987952
#define OFF_SCSRH 46087952
#define OFF_SCSRN 47687952

extern "C" void kernel_launch(void* const* d_in, const int* in_sizes, int n_in,
                              void* d_out, int out_size, void* d_ws, size_t ws_size,
                              hipStream_t stream) {
    const void* x0        = d_in[0];
    const void* node_idx  = d_in[1];
    const void* hedge_idx = d_in[2];
    const void* v2e_K  = d_in[4];
    const void* v2e_Q  = d_in[5];
    const void* v2e_V  = d_in[6];
    const void* v2e_W1 = d_in[7];
    const void* v2e_W2 = d_in[8];
    const void* v2e_ln0_g = d_in[9];
    const void* v2e_ln0_b = d_in[10];
    const void* v2e_ln1_g = d_in[11];
    const void* v2e_ln1_b = d_in[12];
    const void* e2v_K  = d_in[13];
    const void* e2v_Q  = d_in[14];
    const void* e2v_V  = d_in[15];
    const void* e2v_W1 = d_in[16];
    const void* e2v_W2 = d_in[17];
    const void* e2v_ln0_g = d_in[18];
    const void* e2v_ln0_b = d_in[19];
    const void* e2v_ln1_g = d_in[20];
    const void* e2v_ln1_b = d_in[21];

    float* out = (float*)d_out;
    float* out_x0 = out;
    float* out_x1 = out + (size_t)N_NODES_C * HID_C;

    char* base = (char*)d_ws;
    float*    kq1   = (float*)(base + OFF_KQ1);
    float*    kq2   = (float*)(base + OFF_KQ2);
    float*    qgb1  = (float*)(base + OFF_QGB1);
    float*    ep1   = (float*)(base + OFF_EP1);
    float*    qgb2  = (float*)(base + OFF_QGB2);
    float*    ep2   = (float*)(base + OFF_EP2);
    float*    ea    = (float*)(base + OFF_EA);
    ushort_t* Vt1b  = (ushort_t*)(base + OFF_VT1B);
    ushort_t* Vt2b  = (ushort_t*)(base + OFF_VT2B);
    ushort_t* W1tA  = (ushort_t*)(base + OFF_W1TA);
    ushort_t* W2tA  = (ushort_t*)(base + OFF_W2TA);
    ushort_t* W1tB  = (ushort_t*)(base + OFF_W1TB);
    ushort_t* W2tB  = (ushort_t*)(base + OFF_W2TB);
    ushort_t* vb    = (ushort_t*)(base + OFF_VB);
    ushort_t* xlnbf = (ushort_t*)(base + OFF_XLNBF);
    int*      flags = (int*)(base + OFF_FLAGS);
    int*      fill_h = (int*)(base + OFF_FILLH);
    int*      fill_n = (int*)(base + OFF_FILLN);
    ushort_t* scsr_h = (ushort_t*)(base + OFF_SCSRH);
    ushort_t* scsr_n = (ushort_t*)(base + OFF_SCSRN);

    init_kernel<<<INIT_GRID, 256, 0, stream>>>(
        (const unsigned*)x0, (const unsigned*)node_idx, flags,
        (unsigned*)fill_h, (unsigned*)vb, (unsigned*)ea);

    prep_fill_kernel<<<PF_GRID, 256, 0, stream>>>(
        node_idx, hedge_idx, fill_h, fill_n, scsr_h, scsr_n,
        v2e_K, v2e_Q, v2e_V, e2v_K, e2v_Q, e2v_V,
        v2e_W1, v2e_W2, e2v_W1, e2v_W2,
        v2e_ln0_g, v2e_ln0_b, v2e_ln1_g, v2e_ln1_b,
        e2v_ln0_g, e2v_ln0_b, e2v_ln1_g, e2v_ln1_b,
        flags, kq1, kq2, Vt1b, Vt2b, W1tA, W2tA, W1tB, W2tB,
        qgb1, ep1, qgb2, ep2);

    // ----- block 1: vertices -> hyperedges -----
    gemm_x0_kernel<<<dim3((N_NODES_C + 63) / 64, 2), 256, 0, stream>>>(
        x0, flags, Vt1b, vb, N_NODES_C, C_IN_C, kq1, ea);
    attn_ln_kernel<<<N_HEDGES_C / 4, 256, 0, stream>>>(
        fill_h, scsr_h, (const char*)ea, (const char*)vb, qgb1, (uint2*)xlnbf,
        25000);
    fused_mlp_ln_kernel<<<(N_HEDGES_C + 31) / 32, 512, 0, stream>>>(
        xlnbf, W1tA, W2tA, ep1, out_x1, N_HEDGES_C,
        Vt2b, kq2, vb, ea,
        (unsigned*)vb + 12500 * 128, ea + 50000);

    // ----- block 2: hyperedges -> vertices -----
    attn_ln_kernel<<<N_NODES_C / 4, 256, 0, stream>>>(
        fill_n, scsr_n, (const char*)ea, (const char*)vb, qgb2, (uint2*)xlnbf,
        12500);
    fused_mlp_ln_kernel<<<(N_NODES_C + 31) / 32, 512, 0, stream>>>(
        xlnbf, W1tB, W2tB, ep2, out_x0, N_NODES_C,
        nullptr, nullptr, nullptr, nullptr, nullptr, nullptr);
}

// Round 9
// 181.159 us; speedup vs baseline: 1.3349x; 1.0193x over previous
//
#include <hip/hip_runtime.h>
#include <hip/hip_bf16.h>

#define N_NODES_C 25000
#define N_HEDGES_C 12500
#define NNZ_C 400000
#define C_IN_C 128
#define HID_C 256
#define LN_EPS_C 1e-5f
#define CSR_STRIDE 64

typedef unsigned short ushort_t;
typedef __attribute__((ext_vector_type(8))) short short8;
typedef __attribute__((ext_vector_type(4))) float f32x4;

union U4S8 { uint4 u; short8 s; };

__device__ __forceinline__ float ldsel(const void* p, size_t i, bool f32) {
    return f32 ? ((const float*)p)[i] : __bfloat162float(((const __hip_bfloat16*)p)[i]);
}
__device__ __forceinline__ int ldidx(const void* p, size_t i, bool i64) {
    return i64 ? (int)((const long long*)p)[i] : ((const int*)p)[i];
}
__device__ __forceinline__ ushort_t bfbits(float f) {
    union { float f; unsigned u; } v; v.f = f;
    unsigned r = v.u + 0x7FFF + ((v.u >> 16) & 1);
    return (ushort_t)(r >> 16);
}
__device__ __forceinline__ float blo(unsigned u) {
    union { unsigned u; float f; } v; v.u = u << 16; return v.f;
}
__device__ __forceinline__ float bhi(unsigned u) {
    union { unsigned u; float f; } v; v.u = u & 0xFFFF0000u; return v.f;
}

// ---------------------------------------------------------------------------
// init (r6): block 0 = dtype sniff; rest zero counters + vb dummy row + ea
// dummy slots.  attn clamps pad slots, so no scsr dummy-fill needed.
// ---------------------------------------------------------------------------
#define INIT_GRID 148   // 1 + (37500+128+4 -> 37632)/256
__global__ void __launch_bounds__(256)
init_kernel(const unsigned* __restrict__ x0w, const unsigned* __restrict__ idxw,
            int* __restrict__ flags, unsigned* __restrict__ cnts,
            unsigned* __restrict__ vb32, unsigned* __restrict__ ea32) {
    int bid = blockIdx.x;
    if (bid == 0) {
        __shared__ int cnt[2];
        int t = threadIdx.x;
        if (t < 2) cnt[t] = 0;
        __syncthreads();
        int c0 = 0, c1 = 0;
        for (int k = 0; k < 4; k++) {
            unsigned w = x0w[t * 4 + k];
            unsigned elo = (w >> 7) & 0xFF;
            if (elo >= 100 && elo <= 134) c0++;
            if (idxw[2 * (t * 4 + k) + 1] == 0) c1++;
        }
        atomicAdd(&cnt[0], c0);
        atomicAdd(&cnt[1], c1);
        __syncthreads();
        if (t == 0) {
            flags[0] = (cnt[0] < 512) ? 1 : 0;  // 1 => floats are f32
            flags[1] = (cnt[1] >= 512) ? 1 : 0; // 1 => indices are int64
        }
        return;
    }
    int i = (bid - 1) * 256 + threadIdx.x;
    if (i < 37500) { cnts[i] = 0u; return; }
    i -= 37500;
    if (i < 128) { vb32[25000 * 128 + i] = 0u; return; }
    i -= 128;
    if (i < 4) ea32[100000 + i] = 0u;
}

// ---------------------------------------------------------------------------
// prep_fill (r6 structure, proven; r8 nt-load experiment reverted — neutral).
//  blocks [0, 3128): XCD-sliced padded-CSR fill.
//  blocks [3128, ..): prep (kq dots, V/W transposes -> bf16, f32 tables).
// Fill floor is ~43-52us across 4 variants (r4/r5/r6/r8) — do not re-chase.
// ---------------------------------------------------------------------------
#define FILL_CHUNK 1024
#define FILL_NCHUNK ((NNZ_C + FILL_CHUNK - 1) / FILL_CHUNK)   // 391
#define FILL_BLOCKS (8 * FILL_NCHUNK)                         // 3128
#define HSLICE_SZ 1563
#define NSLICE_SZ 3125
#define PREP_TOTAL 364544
#define PREP_BLOCKS ((PREP_TOTAL + 255) / 256)                // 1424
#define PF_GRID (FILL_BLOCKS + PREP_BLOCKS)                   // 4552

__global__ void __launch_bounds__(256)
prep_fill_kernel(const void* __restrict__ node_idx, const void* __restrict__ hedge_idx,
                 int* __restrict__ fill_h, int* __restrict__ fill_n,
                 ushort_t* __restrict__ scsr_h, ushort_t* __restrict__ scsr_n,
                 const void* __restrict__ K1, const void* __restrict__ Q1,
                 const void* __restrict__ V1,
                 const void* __restrict__ K2, const void* __restrict__ Q2,
                 const void* __restrict__ V2,
                 const void* __restrict__ W1a, const void* __restrict__ W2a,
                 const void* __restrict__ W1b, const void* __restrict__ W2b,
                 const void* __restrict__ G0a, const void* __restrict__ B0a,
                 const void* __restrict__ G1a, const void* __restrict__ B1a,
                 const void* __restrict__ G0b, const void* __restrict__ B0b,
                 const void* __restrict__ G1b, const void* __restrict__ B1b,
                 const int* __restrict__ flags,
                 float* __restrict__ kq1, float* __restrict__ kq2,
                 ushort_t* __restrict__ Vt1b, ushort_t* __restrict__ Vt2b,
                 ushort_t* __restrict__ W1tA, ushort_t* __restrict__ W2tA,
                 ushort_t* __restrict__ W1tB, ushort_t* __restrict__ W2tB,
                 float* __restrict__ qgb1, float* __restrict__ ep1,
                 float* __restrict__ qgb2, float* __restrict__ ep2) {
    if (blockIdx.x < FILL_BLOCKS) {
        bool i64 = flags[1] != 0;
        int s = blockIdx.x & 7;
        int chunk = blockIdx.x >> 3;
        int e0 = chunk * FILL_CHUNK;
        int e1 = e0 + FILL_CHUNK; if (e1 > NNZ_C) e1 = NNZ_C;
        int hlo = s * HSLICE_SZ, hhi = hlo + HSLICE_SZ;
        int nlo = s * NSLICE_SZ, nhi = nlo + NSLICE_SZ;
        for (int e = e0 + threadIdx.x; e < e1; e += 256) {
            int nd = ldidx(node_idx, e, i64);
            int he = ldidx(hedge_idx, e, i64);
            if (he >= hlo && he < hhi) {
                int p = atomicAdd(&fill_h[he], 1);
                if (p < CSR_STRIDE) scsr_h[(he << 6) + p] = (ushort_t)nd;
            }
            if (nd >= nlo && nd < nhi) {
                int p = atomicAdd(&fill_n[nd], 1);
                if (p < CSR_STRIDE) scsr_n[(nd << 6) + p] = (ushort_t)he;
            }
        }
        return;
    }
    bool f32 = flags[0] != 0;
    size_t i = (size_t)(blockIdx.x - FILL_BLOCKS) * 256 + threadIdx.x;
    if (i >= PREP_TOTAL) return;
    if (i < 512) {
        int h = (int)(i >> 7), c = (int)(i & 127);
        float s = 0.f;
        for (int d = 0; d < 64; d++)
            s += ldsel(K1, (size_t)(h * 128 + c) * 64 + d, f32) * ldsel(Q1, h * 64 + d, f32);
        kq1[h * 128 + c] = s;
        return;
    }
    i -= 512;
    if (i < 1024) {
        int h = (int)(i >> 8), c = (int)(i & 255);
        float s = 0.f;
        for (int d = 0; d < 64; d++)
            s += ldsel(K2, (size_t)(h * 256 + c) * 64 + d, f32) * ldsel(Q2, h * 64 + d, f32);
        kq2[h * 256 + c] = s;
        return;
    }
    i -= 1024;
    if (i < 32768) {
        int j = (int)(i >> 7), c = (int)(i & 127);
        int h = j >> 6, d = j & 63;
        Vt1b[i] = bfbits(ldsel(V1, (size_t)(h * 128 + c) * 64 + d, f32));
        return;
    }
    i -= 32768;
    if (i < 65536) {
        int j = (int)(i >> 8), c = (int)(i & 255);
        int h = j >> 6, d = j & 63;
        Vt2b[i] = bfbits(ldsel(V2, (size_t)(h * 256 + c) * 64 + d, f32));
        return;
    }
    i -= 65536;
    if (i < 65536) { int n = (int)(i >> 8), k = (int)(i & 255);
        W1tA[i] = bfbits(ldsel(W1a, (size_t)k * 256 + n, f32)); return; }
    i -= 65536;
    if (i < 65536) { int n = (int)(i >> 8), k = (int)(i & 255);
        W2tA[i] = bfbits(ldsel(W2a, (size_t)k * 256 + n, f32)); return; }
    i -= 65536;
    if (i < 65536) { int n = (int)(i >> 8), k = (int)(i & 255);
        W1tB[i] = bfbits(ldsel(W1b, (size_t)k * 256 + n, f32)); return; }
    i -= 65536;
    if (i < 65536) { int n = (int)(i >> 8), k = (int)(i & 255);
        W2tB[i] = bfbits(ldsel(W2b, (size_t)k * 256 + n, f32)); return; }
    i -= 65536;
    {
        int which = (int)(i >> 8);
        int j = (int)(i & 255);
        const void* src; float* dst;
        switch (which) {
            case 0: src = Q1;  dst = qgb1;       break;
            case 1: src = G0a; dst = qgb1 + 256; break;
            case 2: src = B0a; dst = qgb1 + 512; break;
            case 3: src = G1a; dst = ep1;        break;
            case 4: src = B1a; dst = ep1 + 256;  break;
            case 5: src = Q2;  dst = qgb2;       break;
            case 6: src = G0b; dst = qgb2 + 256; break;
            case 7: src = B0b; dst = qgb2 + 512; break;
            case 8: src = G1b; dst = ep2;        break;
            default: src = B1b; dst = ep2 + 256;  break;
        }
        dst[j] = ldsel(src, j, f32);
    }
}

// ---------------------------------------------------------------------------
// gemm_x0 + fused expalpha dir-1 (proven r3/r6)
// ---------------------------------------------------------------------------
__global__ void __launch_bounds__(256)
gemm_x0_kernel(const void* __restrict__ x0, const int* __restrict__ flags,
               const ushort_t* __restrict__ Bt, ushort_t* __restrict__ C,
               int M, int K, const float* __restrict__ kq, float* __restrict__ ea) {
    __shared__ ushort_t As[64 * 72];
    __shared__ ushort_t Bs[128 * 72];
    __shared__ float kqs[512];          // kq1: [4][128]
    bool f32 = flags[0] != 0;
    int tid = threadIdx.x;
    int w = tid >> 6, lane = tid & 63;
    int l15 = lane & 15, kg = lane >> 4;
    int wr = w >> 1, wc = w & 1;
    int row0 = blockIdx.x * 64, col0 = blockIdx.y * 128;
    bool doEa = (blockIdx.y == 0);
    kqs[tid] = kq[tid];
    kqs[256 + tid] = kq[256 + tid];
    __syncthreads();
    f32x4 acc[2][4] = {{{0.f,0.f,0.f,0.f},{0.f,0.f,0.f,0.f},{0.f,0.f,0.f,0.f},{0.f,0.f,0.f,0.f}},
                       {{0.f,0.f,0.f,0.f},{0.f,0.f,0.f,0.f},{0.f,0.f,0.f,0.f},{0.f,0.f,0.f,0.f}}};
    float hd[2][4] = {{0.f,0.f,0.f,0.f},{0.f,0.f,0.f,0.f}};
    int r_ = tid >> 3, ch = tid & 7;
    for (int k0 = 0; k0 < K; k0 += 64) {
#pragma unroll
        for (int p = 0; p < 2; p++) {
            int r = p * 32 + r_;
            uint4 av = {0u,0u,0u,0u};
            int gr = row0 + r;
            if (gr < M) {
                float fv[8];
                if (!f32) {
                    av = *(const uint4*)((const ushort_t*)x0 + (size_t)gr * K + k0 + ch * 8);
                    if (doEa) {
                        unsigned* uw = (unsigned*)&av;
#pragma unroll
                        for (int jj = 0; jj < 4; jj++) { fv[2 * jj] = blo(uw[jj]); fv[2 * jj + 1] = bhi(uw[jj]); }
                    }
                } else {
                    const float* ap = (const float*)x0 + (size_t)gr * K + k0 + ch * 8;
                    float4 f0 = *(const float4*)ap;
                    float4 f1 = *(const float4*)(ap + 4);
                    av.x = (unsigned)bfbits(f0.x) | ((unsigned)bfbits(f0.y) << 16);
                    av.y = (unsigned)bfbits(f0.z) | ((unsigned)bfbits(f0.w) << 16);
                    av.z = (unsigned)bfbits(f1.x) | ((unsigned)bfbits(f1.y) << 16);
                    av.w = (unsigned)bfbits(f1.z) | ((unsigned)bfbits(f1.w) << 16);
                    if (doEa) {
                        fv[0] = f0.x; fv[1] = f0.y; fv[2] = f0.z; fv[3] = f0.w;
                        fv[4] = f1.x; fv[5] = f1.y; fv[6] = f1.z; fv[7] = f1.w;
                    }
                }
                if (doEa) {
                    int c = k0 + ch * 8;
#pragma unroll
                    for (int h = 0; h < 4; h++) {
                        float s = 0.f;
#pragma unroll
                        for (int j = 0; j < 8; j++) s += fv[j] * kqs[h * 128 + c + j];
                        hd[p][h] += s;
                    }
                }
            }
            *(uint4*)&As[r * 72 + ch * 8] = av;
        }
#pragma unroll
        for (int p = 0; p < 4; p++) {
            int i = p * 256 + tid;
            int r2 = i >> 3, c2 = i & 7;
            uint4 bv = *(const uint4*)(Bt + (size_t)(col0 + r2) * K + k0 + c2 * 8);
            *(uint4*)&Bs[r2 * 72 + c2 * 8] = bv;
        }
        __syncthreads();
#pragma unroll
        for (int kk = 0; kk < 2; kk++) {
            U4S8 a0_, a1_;
            a0_.u = *(const uint4*)&As[(32 * wr + l15) * 72 + kk * 32 + kg * 8];
            a1_.u = *(const uint4*)&As[(32 * wr + 16 + l15) * 72 + kk * 32 + kg * 8];
#pragma unroll
            for (int n = 0; n < 4; n++) {
                U4S8 b; b.u = *(const uint4*)&Bs[(64 * wc + 16 * n + l15) * 72 + kk * 32 + kg * 8];
                acc[0][n] = __builtin_amdgcn_mfma_f32_16x16x32_bf16(a0_.s, b.s, acc[0][n], 0, 0, 0);
                acc[1][n] = __builtin_amdgcn_mfma_f32_16x16x32_bf16(a1_.s, b.s, acc[1][n], 0, 0, 0);
            }
        }
        __syncthreads();
    }
#pragma unroll
    for (int m = 0; m < 2; m++) {
#pragma unroll
        for (int n = 0; n < 4; n++) {
#pragma unroll
            for (int rr = 0; rr < 4; rr++) {
                int row = row0 + 32 * wr + 16 * m + kg * 4 + rr;
                if (row < M)
                    C[(size_t)row * 256 + col0 + 64 * wc + 16 * n + l15] = bfbits(acc[m][n][rr]);
            }
        }
    }
    if (doEa) {
#pragma unroll
        for (int p = 0; p < 2; p++) {
#pragma unroll
            for (int msk = 1; msk < 8; msk <<= 1) {
                hd[p][0] += __shfl_xor(hd[p][0], msk);
                hd[p][1] += __shfl_xor(hd[p][1], msk);
                hd[p][2] += __shfl_xor(hd[p][2], msk);
                hd[p][3] += __shfl_xor(hd[p][3], msk);
            }
            if (ch == 0) {
                int row = row0 + p * 32 + r_;
                if (row < M) {
                    float4 o;
                    o.x = __expf(hd[p][0]); o.y = __expf(hd[p][1]);
                    o.z = __expf(hd[p][2]); o.w = __expf(hd[p][3]);
                    *(float4*)(ea + (size_t)row * 4) = o;
                }
            }
        }
    }
}

// ---------------------------------------------------------------------------
// r9 FUSION: attention+LN0 (phase 0) + MLP+LN1 (+ dir-1 extras) in one
// kernel.  Each of 8 waves runs the proven 1-wave attention body for 4
// targets, writing LN0 output (bf16) into LDS xs[32][264]; phases 1-3 read
// A-fragments straight from xs (A-staging and the xlnbf global round-trip
// both eliminated; epilogue residual also reads xs).  Homogeneous footprint
// (every block identical) — avoids the r7 heterogeneous-merge trap.
// dir1 outputs go to vb2/ea2 (NOT vb/ea: phase 0 of the same dispatch still
// reads vb/ea — fresh buffers break the same-dispatch race).
// LDS = 36.9K(Bs) + 16.5K(hs) + 16.5K(xs) + 1K + 4K(kqs) = 74K -> 2 blk/CU.
// ---------------------------------------------------------------------------
#define LOADB4(SRC, KO) { \
    bv0 = *(const uint4*)((SRC) + (size_t)rb * 256 + (KO) + cb * 8); \
    bv1 = *(const uint4*)((SRC) + (size_t)(rb + 64) * 256 + (KO) + cb * 8); \
    bv2 = *(const uint4*)((SRC) + (size_t)(rb + 128) * 256 + (KO) + cb * 8); \
    bv3 = *(const uint4*)((SRC) + (size_t)(rb + 192) * 256 + (KO) + cb * 8); }
#define WRITEB4() { \
    *(uint4*)&Bs[rb * 72 + cb * 8] = bv0; \
    *(uint4*)&Bs[(rb + 64) * 72 + cb * 8] = bv1; \
    *(uint4*)&Bs[(rb + 128) * 72 + cb * 8] = bv2; \
    *(uint4*)&Bs[(rb + 192) * 72 + cb * 8] = bv3; }

#define DECL_BANKD(B) float e##B##0, e##B##1, e##B##2, e##B##3; \
                      uint2 u##B##0, u##B##1, u##B##2, u##B##3;
#define ISSUED1(B, n, sl) { \
    int _i = ((sl) < cnt) ? __shfl(myidx, (sl)) : dummyIdx; \
    int _o = _i << 9; \
    u##B##n = *(const uint2*)(vbL + _o); \
    e##B##n = *(const float*)(eaL + (_o >> 5)); }
#define ISSUED4(B, base) ISSUED1(B,0,(base)) ISSUED1(B,1,(base)+1) ISSUED1(B,2,(base)+2) ISSUED1(B,3,(base)+3)
#define EATD1(B, n) { \
    float wgt = e##B##n; \
    den += wgt; \
    a0 += wgt * blo(u##B##n.x); a1 += wgt * bhi(u##B##n.x); \
    a2 += wgt * blo(u##B##n.y); a3 += wgt * bhi(u##B##n.y); }
#define EATD4(B) EATD1(B,0) EATD1(B,1) EATD1(B,2) EATD1(B,3)

__global__ void __launch_bounds__(512)
fused_attn_mlp_kernel(const int* __restrict__ cnts, const ushort_t* __restrict__ scsr,
                      const char* __restrict__ eaB, const char* __restrict__ vbB,
                      const float* __restrict__ qgb, int dummyIdx,
                      const ushort_t* __restrict__ W1t, const ushort_t* __restrict__ W2t,
                      const float* __restrict__ ep,
                      float* __restrict__ outF, int M,
                      const ushort_t* __restrict__ Vt2b, const float* __restrict__ kq,
                      ushort_t* __restrict__ vbOut, float* __restrict__ eaOut,
                      unsigned* __restrict__ zrow, float* __restrict__ zea) {
    __shared__ ushort_t Bs[256 * 72];
    __shared__ ushort_t hs[32 * 264];
    __shared__ ushort_t xs[32 * 264];
    __shared__ float s1s[32][4];
    __shared__ float s2s[32][4];
    __shared__ float kqs[1024];         // kq2: [4][256] (dir1 only)
    int tid = threadIdx.x;
    int w = tid >> 6, lane = tid & 63;
    int l15 = lane & 15, kg = lane >> 4;
    int wr = w >> 2, wc = w & 3;
    int row0 = blockIdx.x * 32;
    bool dir1 = (Vt2b != nullptr);
    if (dir1) { kqs[tid] = kq[tid]; kqs[512 + tid] = kq[512 + tid]; }
    int rb = tid >> 3, cb = tid & 7;        // B staging: rows rb(+64..), 16B @ cb
    uint4 bv0, bv1, bv2, bv3;
    LOADB4(W1t, 0);                         // phase-1 prologue hides under attn
    // ---------------- phase 0: attention + LN0 -> xs (bf16) ----------------
    {
        const char* vbL = vbB + (lane << 3);
        const char* eaL = eaB + ((lane >> 4) << 2);
        for (int t = 0; t < 4; t++) {
            int tl = (w << 2) + t;          // local row 0..31
            int wid = row0 + tl;
            int cnt = 0, myidx = dummyIdx;
            if (wid < M) {
                cnt = cnts[wid];
                if (cnt > CSR_STRIDE) cnt = CSR_STRIDE;
                myidx = (int)scsr[(wid << 6) + lane];
            }
            float a0 = 0.f, a1 = 0.f, a2 = 0.f, a3 = 0.f, den = 0.f;
            int kr = (cnt + 3) & ~3;
            DECL_BANKD(A)
            DECL_BANKD(B)
            if (kr > 0) { ISSUED4(A, 0) }
            for (int k = 0; k < kr; k += 8) {
                int kb = k + 4;
                bool hasB = kb < kr;
                if (hasB) { ISSUED4(B, kb) }
                EATD4(A)
                int ka = k + 8;
                if (ka < kr) { ISSUED4(A, ka) }
                if (hasB) { EATD4(B) }
            }
            float inv = (den > 0.f) ? (1.f / den) : 0.f;
            int c0i = lane << 2;
            float o0 = a0 * inv + qgb[c0i];
            float o1 = a1 * inv + qgb[c0i + 1];
            float o2 = a2 * inv + qgb[c0i + 2];
            float o3 = a3 * inv + qgb[c0i + 3];
            float part = o0 + o1 + o2 + o3;
#pragma unroll
            for (int m = 32; m; m >>= 1) part += __shfl_xor(part, m);
            float mean = part * (1.f / 256.f);
            float d0 = o0 - mean, d1 = o1 - mean, d2 = o2 - mean, d3 = o3 - mean;
            float p2 = d0 * d0 + d1 * d1 + d2 * d2 + d3 * d3;
#pragma unroll
            for (int m = 32; m; m >>= 1) p2 += __shfl_xor(p2, m);
            float rs = rsqrtf(p2 * (1.f / 256.f) + LN_EPS_C);
            float r0 = d0 * rs * qgb[256 + c0i] + qgb[512 + c0i];
            float r1 = d1 * rs * qgb[256 + c0i + 1] + qgb[512 + c0i + 1];
            float r2 = d2 * rs * qgb[256 + c0i + 2] + qgb[512 + c0i + 2];
            float r3 = d3 * rs * qgb[256 + c0i + 3] + qgb[512 + c0i + 3];
            uint2 outw;
            outw.x = ((unsigned)bfbits(r1) << 16) | bfbits(r0);
            outw.y = ((unsigned)bfbits(r3) << 16) | bfbits(r2);
            *(uint2*)&xs[tl * 264 + c0i] = outw;
        }
    }
    f32x4 acc[4] = {{0.f,0.f,0.f,0.f},{0.f,0.f,0.f,0.f},{0.f,0.f,0.f,0.f},{0.f,0.f,0.f,0.f}};
    // ---------------- phase 1: h = relu(xs @ W1) ----------------
    for (int k0 = 0; k0 < 256; k0 += 64) {
        WRITEB4();
        __syncthreads();                    // covers xs writes (phase 0) too
        if (k0 < 192) LOADB4(W1t, k0 + 64);
#pragma unroll
        for (int kk = 0; kk < 2; kk++) {
            U4S8 a0_;
            a0_.u = *(const uint4*)&xs[(16 * wr + l15) * 264 + k0 + kk * 32 + kg * 8];
#pragma unroll
            for (int n = 0; n < 4; n++) {
                U4S8 b; b.u = *(const uint4*)&Bs[(64 * wc + 16 * n + l15) * 72 + kk * 32 + kg * 8];
                acc[n] = __builtin_amdgcn_mfma_f32_16x16x32_bf16(a0_.s, b.s, acc[n], 0, 0, 0);
            }
        }
        __syncthreads();
    }
    // phase-2 prologue loads issued early (overlap with hs store)
    LOADB4(W2t, 0);
    // relu + bf16 into hs
#pragma unroll
    for (int n = 0; n < 4; n++) {
#pragma unroll
        for (int rr = 0; rr < 4; rr++) {
            int br = 16 * wr + kg * 4 + rr;
            hs[br * 264 + 64 * wc + 16 * n + l15] = bfbits(fmaxf(acc[n][rr], 0.f));
            acc[n][rr] = 0.f;
        }
    }
    __syncthreads();
    // ---------------- phase 2: y = hs @ W2 ----------------
    for (int k0 = 0; k0 < 256; k0 += 64) {
        WRITEB4();
        __syncthreads();
        if (k0 < 192) LOADB4(W2t, k0 + 64);
#pragma unroll
        for (int kk = 0; kk < 2; kk++) {
            U4S8 a0_;
            a0_.u = *(const uint4*)&hs[(16 * wr + l15) * 264 + k0 + kk * 32 + kg * 8];
#pragma unroll
            for (int n = 0; n < 4; n++) {
                U4S8 b; b.u = *(const uint4*)&Bs[(64 * wc + 16 * n + l15) * 72 + kk * 32 + kg * 8];
                acc[n] = __builtin_amdgcn_mfma_f32_16x16x32_bf16(a0_.s, b.s, acc[n], 0, 0, 0);
            }
        }
        __syncthreads();
    }
    // ------- epilogue: y = xs + relu(acc); LN1; relu; store (residual
    //         read from xs — same bf16 bits the old path read from global) --
    float ym[4][4];
#pragma unroll
    for (int rr = 0; rr < 4; rr++) {
        int br = 16 * wr + kg * 4 + rr;
        float ls1 = 0.f;
#pragma unroll
        for (int n = 0; n < 4; n++) {
            int col = 64 * wc + 16 * n + l15;
            float xv = blo((unsigned)xs[br * 264 + col]);
            float yv = xv + fmaxf(acc[n][rr], 0.f);
            ym[n][rr] = yv;
            ls1 += yv;
        }
#pragma unroll
        for (int msk = 1; msk < 16; msk <<= 1) ls1 += __shfl_xor(ls1, msk);
        if (l15 == 0) s1s[br][wc] = ls1;
    }
    __syncthreads();
    float mean_[4];
#pragma unroll
    for (int rr = 0; rr < 4; rr++) {
        int br = 16 * wr + kg * 4 + rr;
        float mn = (s1s[br][0] + s1s[br][1] + s1s[br][2] + s1s[br][3]) * (1.f / 256.f);
        mean_[rr] = mn;
        float ls2 = 0.f;
#pragma unroll
        for (int n = 0; n < 4; n++) {
            float d = ym[n][rr] - mn;
            ls2 += d * d;
        }
#pragma unroll
        for (int msk = 1; msk < 16; msk <<= 1) ls2 += __shfl_xor(ls2, msk);
        if (l15 == 0) s2s[br][wc] = ls2;
    }
    __syncthreads();
#pragma unroll
    for (int rr = 0; rr < 4; rr++) {
        int br = 16 * wr + kg * 4 + rr;
        int grow = row0 + br;
        float var = (s2s[br][0] + s2s[br][1] + s2s[br][2] + s2s[br][3]) * (1.f / 256.f);
        float rs = rsqrtf(var + LN_EPS_C);
#pragma unroll
        for (int n = 0; n < 4; n++) {
            int col = 64 * wc + 16 * n + l15;
            float rv = (ym[n][rr] - mean_[rr]) * rs * ep[col] + ep[256 + col];
            rv = fmaxf(rv, 0.f);
            if (grow < M) outF[(size_t)grow * 256 + col] = rv;
            if (dir1) hs[br * 264 + col] = bfbits(rv);
        }
    }
    if (!dir1) return;
    // phase 3 accumulates fresh (r2 lesson) + prologue loads issued early
#pragma unroll
    for (int n = 0; n < 4; n++)
#pragma unroll
        for (int rr = 0; rr < 4; rr++) acc[n][rr] = 0.f;
    LOADB4(Vt2b, 0);
    __syncthreads();
    // ---- dir-2 dummy zeroing (vb2/ea2 are write-only in this dispatch) ----
    if (blockIdx.x == 0) {
        if (tid < 128) zrow[tid] = 0u;
        else if (tid < 132) zea[tid - 128] = 0.f;
    }
    // ---- mini-expalpha dir2: ea2 = exp(x1 . kq2), 16 threads/row from hs --
    {
        int rrow = tid >> 4, rch = tid & 15;
        float h0 = 0.f, h1 = 0.f, h2 = 0.f, h3 = 0.f;
#pragma unroll
        for (int q = 0; q < 2; q++) {
            uint4 xv = *(const uint4*)&hs[rrow * 264 + rch * 16 + q * 8];
            const unsigned* uw = (const unsigned*)&xv;
#pragma unroll
            for (int jj = 0; jj < 4; jj++) {
                float xl = blo(uw[jj]), xh = bhi(uw[jj]);
                int c = rch * 16 + q * 8 + jj * 2;
                h0 += xl * kqs[c]       + xh * kqs[c + 1];
                h1 += xl * kqs[256 + c] + xh * kqs[256 + c + 1];
                h2 += xl * kqs[512 + c] + xh * kqs[512 + c + 1];
                h3 += xl * kqs[768 + c] + xh * kqs[768 + c + 1];
            }
        }
#pragma unroll
        for (int msk = 1; msk < 16; msk <<= 1) {
            h0 += __shfl_xor(h0, msk); h1 += __shfl_xor(h1, msk);
            h2 += __shfl_xor(h2, msk); h3 += __shfl_xor(h3, msk);
        }
        int grow = row0 + rrow;
        if (rch == 0 && grow < M) {
            float4 o;
            o.x = __expf(h0); o.y = __expf(h1); o.z = __expf(h2); o.w = __expf(h3);
            *(float4*)(eaOut + (size_t)grow * 4) = o;
        }
    }
    // ---------------- phase 3: vb2 = hs(x1) @ Vt2b ----------------
    for (int k0 = 0; k0 < 256; k0 += 64) {
        WRITEB4();
        __syncthreads();
        if (k0 < 192) LOADB4(Vt2b, k0 + 64);
#pragma unroll
        for (int kk = 0; kk < 2; kk++) {
            U4S8 a0_;
            a0_.u = *(const uint4*)&hs[(16 * wr + l15) * 264 + k0 + kk * 32 + kg * 8];
#pragma unroll
            for (int n = 0; n < 4; n++) {
                U4S8 b; b.u = *(const uint4*)&Bs[(64 * wc + 16 * n + l15) * 72 + kk * 32 + kg * 8];
                acc[n] = __builtin_amdgcn_mfma_f32_16x16x32_bf16(a0_.s, b.s, acc[n], 0, 0, 0);
            }
        }
        __syncthreads();
    }
#pragma unroll
    for (int n = 0; n < 4; n++) {
#pragma unroll
        for (int rr = 0; rr < 4; rr++) {
            int row = row0 + 16 * wr + kg * 4 + rr;
            if (row < M)
                vbOut[(size_t)row * 256 + 64 * wc + 16 * n + l15] = bfbits(acc[n][rr]);
        }
    }
}

// ---------------------------------------------------------------------------
// Workspace byte offsets.  xlnbf region freed -> hosts ea2 + vb2 (fresh
// dir-2 buffers required by the same-dispatch fusion).
// ---------------------------------------------------------------------------
#define OFF_KQ1   0
#define OFF_KQ2   2048
#define OFF_QGB1  6144
#define OFF_EP1   9216
#define OFF_QGB2  11264
#define OFF_EP2   14336
#define OFF_EA    16384      // 100004 floats (dir-1: nodes + dummy)
#define OFF_VT1B  416512
#define OFF_VT2B  482048
#define OFF_W1TA  613120
#define OFF_W2TA  744192
#define OFF_W1TB  875264
#define OFF_W2TB  1006336
#define OFF_VB    1137408    // 25001 rows x 512 B (dir-1: node rows + dummy)
#define OFF_EA2   13937920   // 50004 floats (dir-2: hedges + dummy)
#define OFF_VB2   14145536   // 12501 rows x 512 B (dir-2: hedge rows + dummy)
#define OFF_FLAGS 45937920
#define OFF_FILLH 45937952
#define OFF_FILLN 45987952
#define OFF_SCSRH 46087952
#define OFF_SCSRN 47687952

extern "C" void kernel_launch(void* const* d_in, const int* in_sizes, int n_in,
                              void* d_out, int out_size, void* d_ws, size_t ws_size,
                              hipStream_t stream) {
    const void* x0        = d_in[0];
    const void* node_idx  = d_in[1];
    const void* hedge_idx = d_in[2];
    const void* v2e_K  = d_in[4];
    const void* v2e_Q  = d_in[5];
    const void* v2e_V  = d_in[6];
    const void* v2e_W1 = d_in[7];
    const void* v2e_W2 = d_in[8];
    const void* v2e_ln0_g = d_in[9];
    const void* v2e_ln0_b = d_in[10];
    const void* v2e_ln1_g = d_in[11];
    const void* v2e_ln1_b = d_in[12];
    const void* e2v_K  = d_in[13];
    const void* e2v_Q  = d_in[14];
    const void* e2v_V  = d_in[15];
    const void* e2v_W1 = d_in[16];
    const void* e2v_W2 = d_in[17];
    const void* e2v_ln0_g = d_in[18];
    const void* e2v_ln0_b = d_in[19];
    const void* e2v_ln1_g = d_in[20];
    const void* e2v_ln1_b = d_in[21];

    float* out = (float*)d_out;
    float* out_x0 = out;
    float* out_x1 = out + (size_t)N_NODES_C * HID_C;

    char* base = (char*)d_ws;
    float*    kq1   = (float*)(base + OFF_KQ1);
    float*    kq2   = (float*)(base + OFF_KQ2);
    float*    qgb1  = (float*)(base + OFF_QGB1);
    float*    ep1   = (float*)(base + OFF_EP1);
    float*    qgb2  = (float*)(base + OFF_QGB2);
    float*    ep2   = (float*)(base + OFF_EP2);
    float*    ea    = (float*)(base + OFF_EA);
    float*    ea2   = (float*)(base + OFF_EA2);
    ushort_t* Vt1b  = (ushort_t*)(base + OFF_VT1B);
    ushort_t* Vt2b  = (ushort_t*)(base + OFF_VT2B);
    ushort_t* W1tA  = (ushort_t*)(base + OFF_W1TA);
    ushort_t* W2tA  = (ushort_t*)(base + OFF_W2TA);
    ushort_t* W1tB  = (ushort_t*)(base + OFF_W1TB);
    ushort_t* W2tB  = (ushort_t*)(base + OFF_W2TB);
    ushort_t* vb    = (ushort_t*)(base + OFF_VB);
    ushort_t* vb2   = (ushort_t*)(base + OFF_VB2);
    int*      flags = (int*)(base + OFF_FLAGS);
    int*      fill_h = (int*)(base + OFF_FILLH);
    int*      fill_n = (int*)(base + OFF_FILLN);
    ushort_t* scsr_h = (ushort_t*)(base + OFF_SCSRH);
    ushort_t* scsr_n = (ushort_t*)(base + OFF_SCSRN);

    init_kernel<<<INIT_GRID, 256, 0, stream>>>(
        (const unsigned*)x0, (const unsigned*)node_idx, flags,
        (unsigned*)fill_h, (unsigned*)vb, (unsigned*)ea);

    prep_fill_kernel<<<PF_GRID, 256, 0, stream>>>(
        node_idx, hedge_idx, fill_h, fill_n, scsr_h, scsr_n,
        v2e_K, v2e_Q, v2e_V, e2v_K, e2v_Q, e2v_V,
        v2e_W1, v2e_W2, e2v_W1, e2v_W2,
        v2e_ln0_g, v2e_ln0_b, v2e_ln1_g, v2e_ln1_b,
        e2v_ln0_g, e2v_ln0_b, e2v_ln1_g, e2v_ln1_b,
        flags, kq1, kq2, Vt1b, Vt2b, W1tA, W2tA, W1tB, W2tB,
        qgb1, ep1, qgb2, ep2);

    gemm_x0_kernel<<<dim3((N_NODES_C + 63) / 64, 2), 256, 0, stream>>>(
        x0, flags, Vt1b, vb, N_NODES_C, C_IN_C, kq1, ea);

    // ----- block 1: vertices -> hyperedges (attn + MLP fused) -----
    fused_attn_mlp_kernel<<<(N_HEDGES_C + 31) / 32, 512, 0, stream>>>(
        fill_h, scsr_h, (const char*)ea, (const char*)vb, qgb1, 25000,
        W1tA, W2tA, ep1, out_x1, N_HEDGES_C,
        Vt2b, kq2, vb2, ea2,
        (unsigned*)vb2 + 12500 * 128, ea2 + 50000);

    // ----- block 2: hyperedges -> vertices (attn + MLP fused) -----
    fused_attn_mlp_kernel<<<(N_NODES_C + 31) / 32, 512, 0, stream>>>(
        fill_n, scsr_n, (const char*)ea2, (const char*)vb2, qgb2, 12500,
        W1tB, W2tB, ep2, out_x0, N_NODES_C,
        nullptr, nullptr, nullptr, nullptr, nullptr, nullptr);
}